// Round 1
// baseline (303.106 us; speedup 1.0000x reference)
//
#include <hip/hip_runtime.h>
#include <hip/hip_bf16.h>

#define Bz 2
#define Cc 256
#define Nn 4096
#define NH 4
#define HD 64
#define NG 32
#define CPG 8
#define EPSv 1e-5f

typedef __bf16 bf16x8 __attribute__((ext_vector_type(8)));
typedef float f32x4 __attribute__((ext_vector_type(4)));
using bf16_t = __hip_bfloat16;

#define MFMA(a, b, c) __builtin_amdgcn_mfma_f32_16x16x32_bf16(a, b, c, 0, 0, 0)

__device__ __forceinline__ bf16x8 ldb8(const bf16_t* p) {
  return *reinterpret_cast<const bf16x8*>(p);
}

// ---------------- GroupNorm: per-(b,g) mean / rstd ----------------
__global__ __launch_bounds__(256) void gn_reduce(const float* __restrict__ x,
                                                 float* __restrict__ stats) {
  int bg = blockIdx.x;  // b*NG + g ; group channels are contiguous in memory
  const float4* p4 = reinterpret_cast<const float4*>(x + (size_t)bg * (CPG * Nn));
  float s = 0.f, ss = 0.f;
  for (int i = threadIdx.x; i < CPG * Nn / 4; i += 256) {
    float4 v = p4[i];
    s += v.x + v.y + v.z + v.w;
    ss += v.x * v.x + v.y * v.y + v.z * v.z + v.w * v.w;
  }
#pragma unroll
  for (int off = 32; off > 0; off >>= 1) {
    s += __shfl_down(s, off);
    ss += __shfl_down(ss, off);
  }
  __shared__ float ps[4], pss[4];
  int wid = threadIdx.x >> 6;
  if ((threadIdx.x & 63) == 0) { ps[wid] = s; pss[wid] = ss; }
  __syncthreads();
  if (threadIdx.x == 0) {
    float S = ps[0] + ps[1] + ps[2] + ps[3];
    float SS = pss[0] + pss[1] + pss[2] + pss[3];
    const float inv = 1.f / (float)(CPG * Nn);
    float mean = S * inv;
    float var = SS * inv - mean * mean;
    stats[bg * 2] = mean;
    stats[bg * 2 + 1] = rsqrtf(var + EPSv);
  }
}

// ------------- GroupNorm apply -> norm_t[b][n][c] (bf16) -------------
__global__ __launch_bounds__(256) void gn_apply(const float* __restrict__ x,
    const float* __restrict__ stats, const float* __restrict__ sc,
    const float* __restrict__ bi, bf16_t* __restrict__ normt) {
  int b = blockIdx.y;
  int n0 = blockIdx.x * 128;
  int c = threadIdx.x;
  int g = c / CPG;
  float mean = stats[(b * NG + g) * 2];
  float rstd = stats[(b * NG + g) * 2 + 1];
  float a = rstd * sc[c];
  float bb = bi[c] - mean * a;
  const float* xp = x + ((size_t)b * Cc + c) * Nn;
  bf16_t* op = normt + (size_t)b * Nn * Cc + c;
  for (int j = 0; j < 128; j++) {
    int n = n0 + j;
    op[(size_t)n * Cc] = __float2bfloat16(xp[n] * a + bb);
  }
}

// ---------------- weight fp32 -> bf16 ----------------
__global__ __launch_bounds__(256) void conv_w(const float* __restrict__ wq,
    const float* __restrict__ wo, bf16_t* __restrict__ wqb,
    bf16_t* __restrict__ wob) {
  int i = blockIdx.x * 256 + threadIdx.x;
  if (i < 768 * Cc) wqb[i] = __float2bfloat16(wq[i]);
  if (i < Cc * Cc) wob[i] = __float2bfloat16(wo[i]);
}

// ---------------- QKV GEMM: D[n][o] = norm_t[n][:] . Wqkv[o][:] ----------------
// q,k parts written as Qt/Kt[b][h][n][d]; v part LDS-transposed to V[b][h][d][n]
__global__ __launch_bounds__(256) void qkv_gemm(const bf16_t* __restrict__ normt,
    const bf16_t* __restrict__ w, bf16_t* __restrict__ Qt,
    bf16_t* __restrict__ Kt, bf16_t* __restrict__ V) {
  int b = blockIdx.z;
  int o0 = blockIdx.y * 64;
  int n0 = blockIdx.x * 64;
  int wid = threadIdx.x >> 6;
  int lane = threadIdx.x & 63;
  int lr = lane & 15, lk = lane >> 4;
  const bf16_t* an = normt + ((size_t)b * Nn + n0 + wid * 16 + lr) * Cc + lk * 8;
  const bf16_t* bw = w + (size_t)(o0 + lr) * Cc + lk * 8;
  f32x4 acc[4] = {};
#pragma unroll
  for (int kk = 0; kk < Cc / 32; kk++) {
    bf16x8 a = ldb8(an + kk * 32);
#pragma unroll
    for (int os = 0; os < 4; os++) {
      bf16x8 bb = ldb8(bw + (size_t)os * 16 * Cc + kk * 32);
      acc[os] = MFMA(a, bb, acc[os]);
    }
  }
  int h = o0 / 192;
  int part = (o0 % 192) / 64;
  if (part < 2) {
    bf16_t* dst = (part == 0 ? Qt : Kt) + (size_t)(b * NH + h) * Nn * HD;
#pragma unroll
    for (int os = 0; os < 4; os++)
#pragma unroll
      for (int r = 0; r < 4; r++) {
        int n = n0 + wid * 16 + lk * 4 + r;
        int d = os * 16 + lr;
        dst[(size_t)n * HD + d] = __float2bfloat16(acc[os][r]);
      }
  } else {
    __shared__ float t[64][68];
#pragma unroll
    for (int os = 0; os < 4; os++)
#pragma unroll
      for (int r = 0; r < 4; r++)
        t[wid * 16 + lk * 4 + r][os * 16 + lr] = acc[os][r];
    __syncthreads();
    bf16_t* dst = V + (size_t)(b * NH + h) * HD * Nn;
    int d = threadIdx.x >> 2;
    int nch = (threadIdx.x & 3) * 16;
#pragma unroll
    for (int j = 0; j < 16; j++)
      dst[(size_t)d * Nn + n0 + nch + j] = __float2bfloat16(t[nch + j][d]);
  }
}

// ---------------- Flash attention, 4 waves x 16 queries, 32 keys/iter ----------------
__global__ __launch_bounds__(256) void attn_kern(const bf16_t* __restrict__ Qt,
    const bf16_t* __restrict__ Kt, const bf16_t* __restrict__ V,
    bf16_t* __restrict__ At) {
  int b = blockIdx.z, h = blockIdx.y;
  int wid = threadIdx.x >> 6;
  int lane = threadIdx.x & 63;
  int lr = lane & 15, lk = lane >> 4;
  int q0 = blockIdx.x * 64 + wid * 16;
  size_t bh = (size_t)(b * NH + h);
  const bf16_t* qp = Qt + (bh * Nn + q0 + lr) * HD + lk * 8;
  bf16x8 aq0 = ldb8(qp);
  bf16x8 aq1 = ldb8(qp + 32);
  const bf16_t* kb = Kt + bh * Nn * HD + lk * 8;
  const bf16_t* vb = V + bh * HD * Nn + lk * 8;
  __shared__ __align__(16) bf16_t plds[4][16 * 40];  // per-wave P buffer, stride 40
  bf16_t* myp = plds[wid];
  f32x4 acc_o[4] = {};
  float m_r[4], l_r[4];
#pragma unroll
  for (int r = 0; r < 4; r++) { m_r[r] = -1e30f; l_r[r] = 0.f; }
  const float lam = 0.0625f * 1.44269504088896f;  // (1/sqrt(C)) * log2(e)
  for (int k0 = 0; k0 < Nn; k0 += 32) {
    f32x4 s0 = {}, s1 = {};
    const bf16_t* krow = kb + (size_t)(k0 + lr) * HD;
    s0 = MFMA(aq0, ldb8(krow), s0);
    s0 = MFMA(aq1, ldb8(krow + 32), s0);
    s1 = MFMA(aq0, ldb8(krow + 16 * HD), s1);
    s1 = MFMA(aq1, ldb8(krow + 16 * HD + 32), s1);
    // rows held by this lane: queries lk*4+r ; col = key lr (+16 for s1)
    float pm[4];
#pragma unroll
    for (int r = 0; r < 4; r++) pm[r] = fmaxf(s0[r], s1[r]);
#pragma unroll
    for (int off = 1; off < 16; off <<= 1)
#pragma unroll
      for (int r = 0; r < 4; r++) pm[r] = fmaxf(pm[r], __shfl_xor(pm[r], off));
    float sf[4], rs[4];
    f32x4 p0, p1;
#pragma unroll
    for (int r = 0; r < 4; r++) {
      float mn = fmaxf(m_r[r], pm[r]);
      sf[r] = exp2f((m_r[r] - mn) * lam);
      m_r[r] = mn;
      p0[r] = exp2f((s0[r] - mn) * lam);
      p1[r] = exp2f((s1[r] - mn) * lam);
      rs[r] = p0[r] + p1[r];
    }
#pragma unroll
    for (int off = 1; off < 16; off <<= 1)
#pragma unroll
      for (int r = 0; r < 4; r++) rs[r] += __shfl_xor(rs[r], off);
#pragma unroll
    for (int r = 0; r < 4; r++) l_r[r] = l_r[r] * sf[r] + rs[r];
#pragma unroll
    for (int dt = 0; dt < 4; dt++)
#pragma unroll
      for (int r = 0; r < 4; r++) acc_o[dt][r] *= sf[r];
    // P (fp32, D-layout) -> bf16 A-layout via per-wave LDS round trip
#pragma unroll
    for (int r = 0; r < 4; r++) {
      int row = lk * 4 + r;
      myp[row * 40 + lr] = __float2bfloat16(p0[r]);
      myp[row * 40 + 16 + lr] = __float2bfloat16(p1[r]);
    }
    bf16x8 pa = ldb8(myp + lr * 40 + lk * 8);  // A[i=lr][kk=lk*8..+7]
#pragma unroll
    for (int dt = 0; dt < 4; dt++) {
      bf16x8 bv = ldb8(vb + (size_t)(dt * 16 + lr) * Nn + k0);
      acc_o[dt] = MFMA(pa, bv, acc_o[dt]);
    }
  }
#pragma unroll
  for (int r = 0; r < 4; r++) l_r[r] = 1.f / l_r[r];
#pragma unroll
  for (int dt = 0; dt < 4; dt++)
#pragma unroll
    for (int r = 0; r < 4; r++) {
      int q = q0 + lk * 4 + r;
      int c = h * HD + dt * 16 + lr;
      At[((size_t)b * Nn + q) * Cc + c] = __float2bfloat16(acc_o[dt][r] * l_r[r]);
    }
}

// ---------------- out GEMM + bias + residual ----------------
__global__ __launch_bounds__(256) void out_gemm(const bf16_t* __restrict__ At,
    const bf16_t* __restrict__ w, const float* __restrict__ bo,
    const float* __restrict__ x, float* __restrict__ out) {
  int b = blockIdx.z;
  int o0 = blockIdx.y * 64;
  int n0 = blockIdx.x * 64;
  int wid = threadIdx.x >> 6;
  int lane = threadIdx.x & 63;
  int lr = lane & 15, lk = lane >> 4;
  const bf16_t* aa = At + ((size_t)b * Nn + n0 + wid * 16 + lr) * Cc + lk * 8;
  const bf16_t* bw = w + (size_t)(o0 + lr) * Cc + lk * 8;
  f32x4 acc[4] = {};
#pragma unroll
  for (int kk = 0; kk < Cc / 32; kk++) {
    bf16x8 a = ldb8(aa + kk * 32);
#pragma unroll
    for (int os = 0; os < 4; os++) {
      bf16x8 bb = ldb8(bw + (size_t)os * 16 * Cc + kk * 32);
      acc[os] = MFMA(a, bb, acc[os]);
    }
  }
  __shared__ float t[64][68];
#pragma unroll
  for (int os = 0; os < 4; os++)
#pragma unroll
    for (int r = 0; r < 4; r++)
      t[wid * 16 + lk * 4 + r][os * 16 + lr] = acc[os][r];
  __syncthreads();
  int orow = threadIdx.x >> 2;
  int nch = (threadIdx.x & 3) * 16;
  size_t base = ((size_t)b * Cc + o0 + orow) * Nn + n0 + nch;
  float bv = bo[o0 + orow];
#pragma unroll
  for (int j = 0; j < 16; j++)
    out[base + j] = t[nch + j][orow] + bv + x[base + j];
}

extern "C" void kernel_launch(void* const* d_in, const int* in_sizes, int n_in,
                              void* d_out, int out_size, void* d_ws, size_t ws_size,
                              hipStream_t stream) {
  const float* x = (const float*)d_in[0];
  const float* gn_scale = (const float*)d_in[1];
  const float* gn_bias = (const float*)d_in[2];
  const float* w_qkv = (const float*)d_in[3];
  const float* w_out = (const float*)d_in[4];
  const float* b_out = (const float*)d_in[5];
  float* out = (float*)d_out;
  char* ws = (char*)d_ws;

  float* stats = (float*)(ws + 0);                    // 512 B
  bf16_t* wqkv_b = (bf16_t*)(ws + 1024);              // 393216 B
  bf16_t* wout_b = (bf16_t*)(ws + 394240);            // 131072 B
  bf16_t* normt = (bf16_t*)(ws + 525312);             // 4 MiB
  bf16_t* Qt = (bf16_t*)(ws + 4719616);               // 4 MiB
  bf16_t* Kt = (bf16_t*)(ws + 8913920);               // 4 MiB
  bf16_t* V = (bf16_t*)(ws + 13108224);               // 4 MiB
  bf16_t* At = (bf16_t*)(ws + 17302528);              // 4 MiB  (total ~20.5 MiB)

  conv_w<<<768, 256, 0, stream>>>(w_qkv, w_out, wqkv_b, wout_b);
  gn_reduce<<<Bz * NG, 256, 0, stream>>>(x, stats);
  gn_apply<<<dim3(Nn / 128, Bz), 256, 0, stream>>>(x, stats, gn_scale, gn_bias, normt);
  qkv_gemm<<<dim3(Nn / 64, 12, Bz), 256, 0, stream>>>(normt, wqkv_b, Qt, Kt, V);
  attn_kern<<<dim3(Nn / 64, NH, Bz), 256, 0, stream>>>(Qt, Kt, V, At);
  out_gemm<<<dim3(Nn / 64, Cc / 64, Bz), 256, 0, stream>>>(At, wout_b, b_out, x, out);
}

// Round 3
// 295.723 us; speedup vs baseline: 1.0250x; 1.0250x over previous
//
#include <hip/hip_runtime.h>
#include <hip/hip_bf16.h>

#define Bz 2
#define Cc 256
#define Nn 4096
#define NH 4
#define HD 64
#define NG 32
#define CPG 8
#define EPSv 1e-5f
#define NSPLIT 2   // key-dim splits for attention
#define GNPART 4   // partial blocks per group in gn_reduce

typedef __bf16 bf16x8 __attribute__((ext_vector_type(8)));
typedef __bf16 bf16x4 __attribute__((ext_vector_type(4)));
typedef float f32x4 __attribute__((ext_vector_type(4)));
using bf16_t = __hip_bfloat16;

#define MFMA(a, b, c) __builtin_amdgcn_mfma_f32_16x16x32_bf16(a, b, c, 0, 0, 0)

__device__ __forceinline__ bf16x8 ldb8(const bf16_t* p) {
  return *reinterpret_cast<const bf16x8*>(p);
}

// ---------------- GroupNorm: partial sums per (b,g,quarter) ----------------
__global__ __launch_bounds__(256) void gn_reduce(const float* __restrict__ x,
                                                 float* __restrict__ stats4) {
  int bg = blockIdx.x;
  int part = blockIdx.y;
  const float4* p4 = reinterpret_cast<const float4*>(
      x + (size_t)bg * (CPG * Nn) + (size_t)part * (CPG * Nn / GNPART));
  float s = 0.f, ss = 0.f;
  for (int i = threadIdx.x; i < CPG * Nn / GNPART / 4; i += 256) {
    float4 v = p4[i];
    s += v.x + v.y + v.z + v.w;
    ss += v.x * v.x + v.y * v.y + v.z * v.z + v.w * v.w;
  }
#pragma unroll
  for (int off = 32; off > 0; off >>= 1) {
    s += __shfl_down(s, off);
    ss += __shfl_down(ss, off);
  }
  __shared__ float ps[4], pss[4];
  int wid = threadIdx.x >> 6;
  if ((threadIdx.x & 63) == 0) { ps[wid] = s; pss[wid] = ss; }
  __syncthreads();
  if (threadIdx.x == 0) {
    stats4[(bg * GNPART + part) * 2] = ps[0] + ps[1] + ps[2] + ps[3];
    stats4[(bg * GNPART + part) * 2 + 1] = pss[0] + pss[1] + pss[2] + pss[3];
  }
}

// ------ GroupNorm apply -> norm_t[b][n][c] bf16, coalesced both sides ------
__global__ __launch_bounds__(256) void gn_apply(const float* __restrict__ x,
    const float* __restrict__ stats4, const float* __restrict__ sc,
    const float* __restrict__ bi, bf16_t* __restrict__ normt) {
  int b = blockIdx.z, c0 = blockIdx.y * 64, n0 = blockIdx.x * 64;
  __shared__ __align__(16) __bf16 t[64][72];
  int cx = threadIdx.x & 15, cy0 = threadIdx.x >> 4;
  const float inv = 1.f / (float)(CPG * Nn);
#pragma unroll
  for (int j = 0; j < 4; j++) {
    int c = c0 + cy0 + j * 16;
    int bg = b * NG + (c >> 3);
    float S = stats4[bg * 8] + stats4[bg * 8 + 2] + stats4[bg * 8 + 4] + stats4[bg * 8 + 6];
    float SS = stats4[bg * 8 + 1] + stats4[bg * 8 + 3] + stats4[bg * 8 + 5] + stats4[bg * 8 + 7];
    float mean = S * inv;
    float rstd = rsqrtf(SS * inv - mean * mean + EPSv);
    float a = rstd * sc[c];
    float bb = bi[c] - mean * a;
    float4 v = *reinterpret_cast<const float4*>(x + ((size_t)b * Cc + c) * Nn + n0 + cx * 4);
    bf16x4 w;
    w[0] = (__bf16)(v.x * a + bb); w[1] = (__bf16)(v.y * a + bb);
    w[2] = (__bf16)(v.z * a + bb); w[3] = (__bf16)(v.w * a + bb);
    *reinterpret_cast<bf16x4*>(&t[cy0 + j * 16][cx * 4]) = w;
  }
  __syncthreads();
  int ny = threadIdx.x >> 2, ch0 = threadIdx.x & 3;
#pragma unroll
  for (int j = 0; j < 2; j++) {
    int ch = ch0 + j * 4;
    bf16x8 o;
#pragma unroll
    for (int jj = 0; jj < 8; jj++) o[jj] = t[ch * 8 + jj][ny];
    *reinterpret_cast<bf16x8*>(normt + ((size_t)b * Nn + n0 + ny) * Cc + c0 + ch * 8) = o;
  }
}

// ---------------- weight fp32 -> bf16 ----------------
__global__ __launch_bounds__(256) void conv_w(const float* __restrict__ wq,
    const float* __restrict__ wo, bf16_t* __restrict__ wqb,
    bf16_t* __restrict__ wob) {
  int i = blockIdx.x * 256 + threadIdx.x;
  if (i < 768 * Cc) wqb[i] = __float2bfloat16(wq[i]);
  if (i < Cc * Cc) wob[i] = __float2bfloat16(wo[i]);
}

// ---------------- QKV GEMM ----------------
__global__ __launch_bounds__(256) void qkv_gemm(const bf16_t* __restrict__ normt,
    const bf16_t* __restrict__ w, bf16_t* __restrict__ Qt,
    bf16_t* __restrict__ Kt, bf16_t* __restrict__ V) {
  int b = blockIdx.z;
  int o0 = blockIdx.y * 64;
  int n0 = blockIdx.x * 64;
  int wid = threadIdx.x >> 6;
  int lane = threadIdx.x & 63;
  int lr = lane & 15, lk = lane >> 4;
  const bf16_t* an = normt + ((size_t)b * Nn + n0 + wid * 16 + lr) * Cc + lk * 8;
  const bf16_t* bw = w + (size_t)(o0 + lr) * Cc + lk * 8;
  f32x4 acc[4] = {};
#pragma unroll
  for (int kk = 0; kk < Cc / 32; kk++) {
    bf16x8 a = ldb8(an + kk * 32);
#pragma unroll
    for (int os = 0; os < 4; os++) {
      bf16x8 bb = ldb8(bw + (size_t)os * 16 * Cc + kk * 32);
      acc[os] = MFMA(a, bb, acc[os]);
    }
  }
  int h = o0 / 192;
  int part = (o0 % 192) / 64;
  if (part < 2) {
    bf16_t* dst = (part == 0 ? Qt : Kt) + (size_t)(b * NH + h) * Nn * HD;
#pragma unroll
    for (int os = 0; os < 4; os++)
#pragma unroll
      for (int r = 0; r < 4; r++) {
        int n = n0 + wid * 16 + lk * 4 + r;
        int d = os * 16 + lr;
        dst[(size_t)n * HD + d] = __float2bfloat16(acc[os][r]);
      }
  } else {
    __shared__ float t[64][68];
#pragma unroll
    for (int os = 0; os < 4; os++)
#pragma unroll
      for (int r = 0; r < 4; r++)
        t[wid * 16 + lk * 4 + r][os * 16 + lr] = acc[os][r];
    __syncthreads();
    bf16_t* dst = V + (size_t)(b * NH + h) * HD * Nn;
    int d = threadIdx.x >> 2;
    int nch = (threadIdx.x & 3) * 16;
#pragma unroll
    for (int j = 0; j < 16; j++)
      dst[(size_t)d * Nn + n0 + nch + j] = __float2bfloat16(t[nch + j][d]);
  }
}

// ---- Flash attention, swapped QK^T (lane-local softmax), 2-way key split ----
// Writes per-split NORMALIZED O (bf16) + per-query (m,l) (fp32).
__global__ __launch_bounds__(256) void attn_kern(const bf16_t* __restrict__ Qt,
    const bf16_t* __restrict__ Kt, const bf16_t* __restrict__ V,
    bf16_t* __restrict__ Opart, float* __restrict__ ml) {
  int z = blockIdx.z;          // z = split*Bz + b
  int b = z & 1, sp = z >> 1;
  int h = blockIdx.y;
  int wid = threadIdx.x >> 6, lane = threadIdx.x & 63;
  int lr = lane & 15, lk = lane >> 4;
  int q0 = blockIdx.x * 64 + wid * 16;
  size_t bh = (size_t)(b * NH + h);
  const bf16_t* qp = Qt + (bh * Nn + q0 + lr) * HD + lk * 8;
  bf16x8 aq0 = ldb8(qp), aq1 = ldb8(qp + 32);
  const bf16_t* kb = Kt + bh * Nn * HD + lk * 8;
  const bf16_t* vrow = V + bh * HD * Nn + (size_t)lr * Nn + lk * 8;
  int kbeg = sp * (Nn / NSPLIT), kend = kbeg + Nn / NSPLIT;

  __shared__ __align__(16) bf16_t plds[4][16 * 40];  // per-wave P, row stride 40 (80B)
  bf16_t* myp = plds[wid];
  f32x4 acc[4] = {};
  float m_r = -1e30f, l_r = 0.f;
  const float lam = 0.0625f * 1.44269504088896f;  // (1/sqrt(C)) * log2(e)

  for (int k0 = kbeg; k0 < kend; k0 += 32) {
    const bf16_t* krow = kb + (size_t)(k0 + lr) * HD;
    f32x4 s0 = {}, s1 = {};
    s0 = MFMA(ldb8(krow), aq0, s0);               // S^T[key][q]
    s0 = MFMA(ldb8(krow + 32), aq1, s0);
    s1 = MFMA(ldb8(krow + 16 * HD), aq0, s1);
    s1 = MFMA(ldb8(krow + 16 * HD + 32), aq1, s1);
    // lane holds keys {lk*4+r, 16+lk*4+r} for query lr
    float pm = fmaxf(fmaxf(fmaxf(s0[0], s0[1]), fmaxf(s0[2], s0[3])),
                     fmaxf(fmaxf(s1[0], s1[1]), fmaxf(s1[2], s1[3])));
    pm = fmaxf(pm, __shfl_xor(pm, 16));
    pm = fmaxf(pm, __shfl_xor(pm, 32));
    if (!__all(pm <= m_r)) {
      float mn = fmaxf(m_r, pm);
      float sf = exp2f((m_r - mn) * lam);
      m_r = mn;
      l_r *= sf;
#pragma unroll
      for (int dt = 0; dt < 4; dt++) acc[dt] = acc[dt] * sf;
    }
    float mnl = m_r * lam;
    f32x4 p0, p1;
#pragma unroll
    for (int r = 0; r < 4; r++) {
      p0[r] = exp2f(s0[r] * lam - mnl);
      p1[r] = exp2f(s1[r] * lam - mnl);
    }
    float rs = ((p0[0] + p0[1]) + (p0[2] + p0[3])) + ((p1[0] + p1[1]) + (p1[2] + p1[3]));
    rs += __shfl_xor(rs, 16);
    rs += __shfl_xor(rs, 32);
    l_r += rs;
    bf16x4 w0, w1;
#pragma unroll
    for (int r = 0; r < 4; r++) { w0[r] = (__bf16)p0[r]; w1[r] = (__bf16)p1[r]; }
    *reinterpret_cast<bf16x4*>(myp + lr * 40 + lk * 4) = w0;        // P[q=lr][keys lk*4..]
    *reinterpret_cast<bf16x4*>(myp + lr * 40 + 16 + lk * 4) = w1;   // P[q=lr][keys 16+lk*4..]
    bf16x8 pa = ldb8(myp + lr * 40 + lk * 8);                       // B-frag: P[q=lr][lk*8+j]
#pragma unroll
    for (int dt = 0; dt < 4; dt++)
      acc[dt] = MFMA(ldb8(vrow + (size_t)dt * 16 * Nn + k0), pa, acc[dt]);  // O^T[d][q]
  }
  float inv_l = 1.f / l_r;
  bf16_t* obase = Opart + (((size_t)z * NH + h) * Nn + q0 + lr) * HD + lk * 4;
#pragma unroll
  for (int dt = 0; dt < 4; dt++) {
    bf16x4 ov;
#pragma unroll
    for (int r = 0; r < 4; r++) ov[r] = (__bf16)(acc[dt][r] * inv_l);
    *reinterpret_cast<bf16x4*>(obase + dt * 16) = ov;
  }
  if (lk == 0) {
    float2 mlv = make_float2(m_r, l_r);
    *reinterpret_cast<float2*>(ml + (((size_t)z * NH + h) * Nn + q0 + lr) * 2) = mlv;
  }
}

// ---------------- merge split-K partials -> At[b][n][c] bf16 ----------------
__global__ __launch_bounds__(256) void attn_merge(const bf16_t* __restrict__ Opart,
    const float* __restrict__ ml, bf16_t* __restrict__ At) {
  int gid = blockIdx.x * 256 + threadIdx.x;
  int d0 = (gid & 7) * 8;
  int q = (gid >> 3) & (Nn - 1);
  int h = (gid >> 15) & (NH - 1);
  int b = gid >> 17;
  const float lam = 0.0625f * 1.44269504088896f;
  size_t zi0 = ((size_t)(0 * Bz + b) * NH + h) * Nn + q;
  size_t zi1 = ((size_t)(1 * Bz + b) * NH + h) * Nn + q;
  float m0 = ml[zi0 * 2], l0 = ml[zi0 * 2 + 1];
  float m1 = ml[zi1 * 2], l1 = ml[zi1 * 2 + 1];
  float M = fmaxf(m0, m1);
  float w0 = l0 * exp2f((m0 - M) * lam);
  float w1 = l1 * exp2f((m1 - M) * lam);
  float invL = 1.f / (w0 + w1);
  bf16x8 a0 = ldb8(Opart + zi0 * HD + d0);
  bf16x8 a1 = ldb8(Opart + zi1 * HD + d0);
  bf16x8 ov;
#pragma unroll
  for (int r = 0; r < 8; r++)
    ov[r] = (__bf16)(((float)a0[r] * w0 + (float)a1[r] * w1) * invL);
  *reinterpret_cast<bf16x8*>(At + ((size_t)b * Nn + q) * Cc + h * HD + d0) = ov;
}

// ---------------- out GEMM + bias + residual ----------------
__global__ __launch_bounds__(256) void out_gemm(const bf16_t* __restrict__ At,
    const bf16_t* __restrict__ w, const float* __restrict__ bo,
    const float* __restrict__ x, float* __restrict__ out) {
  int b = blockIdx.z;
  int o0 = blockIdx.y * 64;
  int n0 = blockIdx.x * 64;
  int wid = threadIdx.x >> 6;
  int lane = threadIdx.x & 63;
  int lr = lane & 15, lk = lane >> 4;
  const bf16_t* aa = At + ((size_t)b * Nn + n0 + wid * 16 + lr) * Cc + lk * 8;
  const bf16_t* bw = w + (size_t)(o0 + lr) * Cc + lk * 8;
  f32x4 acc[4] = {};
#pragma unroll
  for (int kk = 0; kk < Cc / 32; kk++) {
    bf16x8 a = ldb8(aa + kk * 32);
#pragma unroll
    for (int os = 0; os < 4; os++) {
      bf16x8 bb = ldb8(bw + (size_t)os * 16 * Cc + kk * 32);
      acc[os] = MFMA(a, bb, acc[os]);
    }
  }
  __shared__ float t[64][68];
#pragma unroll
  for (int os = 0; os < 4; os++)
#pragma unroll
    for (int r = 0; r < 4; r++)
      t[wid * 16 + lk * 4 + r][os * 16 + lr] = acc[os][r];
  __syncthreads();
  int orow = threadIdx.x >> 2;
  int nch = (threadIdx.x & 3) * 16;
  size_t base = ((size_t)b * Cc + o0 + orow) * Nn + n0 + nch;
  float bv = bo[o0 + orow];
#pragma unroll
  for (int j = 0; j < 16; j++)
    out[base + j] = t[nch + j][orow] + bv + x[base + j];
}

extern "C" void kernel_launch(void* const* d_in, const int* in_sizes, int n_in,
                              void* d_out, int out_size, void* d_ws, size_t ws_size,
                              hipStream_t stream) {
  const float* x = (const float*)d_in[0];
  const float* gn_scale = (const float*)d_in[1];
  const float* gn_bias = (const float*)d_in[2];
  const float* w_qkv = (const float*)d_in[3];
  const float* w_out = (const float*)d_in[4];
  const float* b_out = (const float*)d_in[5];
  float* out = (float*)d_out;
  char* ws = (char*)d_ws;

  // Workspace layout (peak 21,635,072 B ~= 20.6 MiB, ~ R1's proven 20.5 MiB):
  //   [0)        stats4   2 KB
  //   [4096)     wout_b   128 KB
  //   [139264)   Qt       4 MB   (At aliases Qt after attn)
  //   [4333568)  Kt       4 MB
  //   [8527872)  V        4 MB
  //   [12722176) wqkv_b 384 KB + normt 4 MB   -- dead after qkv_gemm
  //   [12722176) Opart (bf16, 4z*4h*4096q*64d = 8 MB)  -- live from attn_kern
  //   [21110784) ml    (fp32, 4z*4h*4096q*2  = 512 KB)
  float* stats4 = (float*)(ws + 0);
  bf16_t* wout_b = (bf16_t*)(ws + 4096);
  bf16_t* Qt = (bf16_t*)(ws + 139264);
  bf16_t* At = (bf16_t*)(ws + 139264);
  bf16_t* Kt = (bf16_t*)(ws + 4333568);
  bf16_t* V = (bf16_t*)(ws + 8527872);
  bf16_t* wqkv_b = (bf16_t*)(ws + 12722176);
  bf16_t* normt = (bf16_t*)(ws + 13115392);
  bf16_t* Opart = (bf16_t*)(ws + 12722176);
  float* ml = (float*)(ws + 21110784);

  conv_w<<<768, 256, 0, stream>>>(w_qkv, w_out, wqkv_b, wout_b);
  gn_reduce<<<dim3(Bz * NG, GNPART), 256, 0, stream>>>(x, stats4);
  gn_apply<<<dim3(Nn / 64, Cc / 64, Bz), 256, 0, stream>>>(x, stats4, gn_scale, gn_bias, normt);
  qkv_gemm<<<dim3(Nn / 64, 12, Bz), 256, 0, stream>>>(normt, wqkv_b, Qt, Kt, V);
  attn_kern<<<dim3(Nn / 64, NH, Bz * NSPLIT), 256, 0, stream>>>(Qt, Kt, V, Opart, ml);
  attn_merge<<<Bz * NH * Nn * HD / 8 / 256, 256, 0, stream>>>(Opart, ml, At);
  out_gemm<<<dim3(Nn / 64, Cc / 64, Bz), 256, 0, stream>>>(At, wout_b, b_out, x, out);
}

// Round 4
// 144.596 us; speedup vs baseline: 2.0962x; 2.0452x over previous
//
#include <hip/hip_runtime.h>
#include <hip/hip_bf16.h>

#define Bz 2
#define Cc 256
#define Nn 4096
#define NH 4
#define HD 64
#define NG 32
#define CPG 8
#define EPSv 1e-5f
#define NSPLIT 2   // key-dim splits for attention
#define GNPART 4   // partial blocks per group in gn_reduce

typedef __bf16 bf16x8 __attribute__((ext_vector_type(8)));
typedef __bf16 bf16x4 __attribute__((ext_vector_type(4)));
typedef float f32x4 __attribute__((ext_vector_type(4)));
using bf16_t = __hip_bfloat16;

#define MFMA(a, b, c) __builtin_amdgcn_mfma_f32_16x16x32_bf16(a, b, c, 0, 0, 0)

#define GLOAD_LDS(g, l)                                                        \
  __builtin_amdgcn_global_load_lds(                                            \
      (const __attribute__((address_space(1))) void*)(g),                      \
      (__attribute__((address_space(3))) void*)(l), 16, 0, 0)

__device__ __forceinline__ bf16x8 ldb8(const bf16_t* p) {
  return *reinterpret_cast<const bf16x8*>(p);
}

// ---------------- GroupNorm: partial sums per (b,g,quarter) ----------------
__global__ __launch_bounds__(256) void gn_reduce(const float* __restrict__ x,
                                                 float* __restrict__ stats4) {
  int bg = blockIdx.x;
  int part = blockIdx.y;
  const float4* p4 = reinterpret_cast<const float4*>(
      x + (size_t)bg * (CPG * Nn) + (size_t)part * (CPG * Nn / GNPART));
  float s = 0.f, ss = 0.f;
  for (int i = threadIdx.x; i < CPG * Nn / GNPART / 4; i += 256) {
    float4 v = p4[i];
    s += v.x + v.y + v.z + v.w;
    ss += v.x * v.x + v.y * v.y + v.z * v.z + v.w * v.w;
  }
#pragma unroll
  for (int off = 32; off > 0; off >>= 1) {
    s += __shfl_down(s, off);
    ss += __shfl_down(ss, off);
  }
  __shared__ float ps[4], pss[4];
  int wid = threadIdx.x >> 6;
  if ((threadIdx.x & 63) == 0) { ps[wid] = s; pss[wid] = ss; }
  __syncthreads();
  if (threadIdx.x == 0) {
    stats4[(bg * GNPART + part) * 2] = ps[0] + ps[1] + ps[2] + ps[3];
    stats4[(bg * GNPART + part) * 2 + 1] = pss[0] + pss[1] + pss[2] + pss[3];
  }
}

// ------ GroupNorm apply -> norm_t[b][n][c] bf16, coalesced both sides ------
__global__ __launch_bounds__(256) void gn_apply(const float* __restrict__ x,
    const float* __restrict__ stats4, const float* __restrict__ sc,
    const float* __restrict__ bi, bf16_t* __restrict__ normt) {
  int b = blockIdx.z, c0 = blockIdx.y * 64, n0 = blockIdx.x * 64;
  __shared__ __align__(16) __bf16 t[64][72];
  int cx = threadIdx.x & 15, cy0 = threadIdx.x >> 4;
  const float inv = 1.f / (float)(CPG * Nn);
#pragma unroll
  for (int j = 0; j < 4; j++) {
    int c = c0 + cy0 + j * 16;
    int bg = b * NG + (c >> 3);
    float S = stats4[bg * 8] + stats4[bg * 8 + 2] + stats4[bg * 8 + 4] + stats4[bg * 8 + 6];
    float SS = stats4[bg * 8 + 1] + stats4[bg * 8 + 3] + stats4[bg * 8 + 5] + stats4[bg * 8 + 7];
    float mean = S * inv;
    float rstd = rsqrtf(SS * inv - mean * mean + EPSv);
    float a = rstd * sc[c];
    float bb = bi[c] - mean * a;
    float4 v = *reinterpret_cast<const float4*>(x + ((size_t)b * Cc + c) * Nn + n0 + cx * 4);
    bf16x4 w;
    w[0] = (__bf16)(v.x * a + bb); w[1] = (__bf16)(v.y * a + bb);
    w[2] = (__bf16)(v.z * a + bb); w[3] = (__bf16)(v.w * a + bb);
    *reinterpret_cast<bf16x4*>(&t[cy0 + j * 16][cx * 4]) = w;
  }
  __syncthreads();
  int ny = threadIdx.x >> 2, ch0 = threadIdx.x & 3;
#pragma unroll
  for (int j = 0; j < 2; j++) {
    int ch = ch0 + j * 4;
    bf16x8 o;
#pragma unroll
    for (int jj = 0; jj < 8; jj++) o[jj] = t[ch * 8 + jj][ny];
    *reinterpret_cast<bf16x8*>(normt + ((size_t)b * Nn + n0 + ny) * Cc + c0 + ch * 8) = o;
  }
}

// ---------------- weight fp32 -> bf16 ----------------
__global__ __launch_bounds__(256) void conv_w(const float* __restrict__ wq,
    const float* __restrict__ wo, bf16_t* __restrict__ wqb,
    bf16_t* __restrict__ wob) {
  int i = blockIdx.x * 256 + threadIdx.x;
  if (i < 768 * Cc) wqb[i] = __float2bfloat16(wq[i]);
  if (i < Cc * Cc) wob[i] = __float2bfloat16(wo[i]);
}

// ---------------- QKV GEMM ----------------
__global__ __launch_bounds__(256) void qkv_gemm(const bf16_t* __restrict__ normt,
    const bf16_t* __restrict__ w, bf16_t* __restrict__ Qt,
    bf16_t* __restrict__ Kt, bf16_t* __restrict__ V) {
  int b = blockIdx.z;
  int o0 = blockIdx.y * 64;
  int n0 = blockIdx.x * 64;
  int wid = threadIdx.x >> 6;
  int lane = threadIdx.x & 63;
  int lr = lane & 15, lk = lane >> 4;
  const bf16_t* an = normt + ((size_t)b * Nn + n0 + wid * 16 + lr) * Cc + lk * 8;
  const bf16_t* bw = w + (size_t)(o0 + lr) * Cc + lk * 8;
  f32x4 acc[4] = {};
#pragma unroll
  for (int kk = 0; kk < Cc / 32; kk++) {
    bf16x8 a = ldb8(an + kk * 32);
#pragma unroll
    for (int os = 0; os < 4; os++) {
      bf16x8 bb = ldb8(bw + (size_t)os * 16 * Cc + kk * 32);
      acc[os] = MFMA(a, bb, acc[os]);
    }
  }
  int h = o0 / 192;
  int part = (o0 % 192) / 64;
  if (part < 2) {
    bf16_t* dst = (part == 0 ? Qt : Kt) + (size_t)(b * NH + h) * Nn * HD;
#pragma unroll
    for (int os = 0; os < 4; os++)
#pragma unroll
      for (int r = 0; r < 4; r++) {
        int n = n0 + wid * 16 + lk * 4 + r;
        int d = os * 16 + lr;
        dst[(size_t)n * HD + d] = __float2bfloat16(acc[os][r]);
      }
  } else {
    __shared__ float t[64][68];
#pragma unroll
    for (int os = 0; os < 4; os++)
#pragma unroll
      for (int r = 0; r < 4; r++)
        t[wid * 16 + lk * 4 + r][os * 16 + lr] = acc[os][r];
    __syncthreads();
    bf16_t* dst = V + (size_t)(b * NH + h) * HD * Nn;
    int d = threadIdx.x >> 2;
    int nch = (threadIdx.x & 3) * 16;
#pragma unroll
    for (int j = 0; j < 16; j++)
      dst[(size_t)d * Nn + n0 + nch + j] = __float2bfloat16(t[nch + j][d]);
  }
}

// ---- Flash attention: 8 waves/block, LDS-staged K/V (dbuf, XOR-swizzled) ----
// K_lds[32][64] (128B rows, slot^=(row&7)); V_lds[64][32] (64B rows,
// slot^=((row>>1)&3)). global_load_lds writes linearly (base+lane*16); the
// per-lane GLOBAL source carries the inverse swizzle (rule #21).
__global__ __launch_bounds__(512, 4) void attn_kern(const bf16_t* __restrict__ Qt,
    const bf16_t* __restrict__ Kt, const bf16_t* __restrict__ V,
    bf16_t* __restrict__ Opart, float* __restrict__ ml) {
  int z = blockIdx.z;          // z = split*Bz + b
  int b = z & 1, sp = z >> 1;
  int h = blockIdx.y;
  int wid = threadIdx.x >> 6, lane = threadIdx.x & 63;
  int lr = lane & 15, lk = lane >> 4;
  int q0 = blockIdx.x * 128 + wid * 16;
  size_t bh = (size_t)(b * NH + h);
  const bf16_t* qp = Qt + (bh * Nn + q0 + lr) * HD + lk * 8;
  bf16x8 aq0 = ldb8(qp), aq1 = ldb8(qp + 32);
  const bf16_t* kglob = Kt + bh * Nn * HD;
  const bf16_t* vglob = V + bh * HD * Nn;
  int kbeg = sp * (Nn / NSPLIT), kend = kbeg + Nn / NSPLIT;

  __shared__ __align__(16) bf16_t kbuf[2][32 * 64];   // 8 KB
  __shared__ __align__(16) bf16_t vbuf[2][64 * 32];   // 8 KB
  __shared__ __align__(16) bf16_t plds[8][16 * 40];   // 10 KB
  bf16_t* myp = plds[wid];

  // per-wave staging source (inverse-swizzled global address), K or V role
  int krow_s = wid * 8 + (lane >> 3);
  int ksl = (lane & 7) ^ (krow_s & 7);
  int vrow_s = (wid - 4) * 16 + (lane >> 2);
  int vsl = (lane & 3) ^ ((vrow_s >> 1) & 3);
  const bf16_t* ksrc = kglob + (size_t)(kbeg + krow_s) * HD + ksl * 8;
  const bf16_t* vsrc = vglob + (size_t)vrow_s * Nn + kbeg + vsl * 8;

  f32x4 acc[4] = {};
  float m_r = -1e30f, l_r = 0.f;
  const float lam = 0.0625f * 1.44269504088896f;  // (1/sqrt(C)) * log2(e)
  const int NT = (Nn / NSPLIT) / 32;

  // prologue: stage tile 0 into buf 0
  if (wid < 4) GLOAD_LDS(ksrc, &kbuf[0][wid * 512]);
  else         GLOAD_LDS(vsrc, &vbuf[0][(wid - 4) * 512]);

  int cur = 0;
  for (int t = 0; t < NT; t++) {
    __syncthreads();  // drains vmcnt/lgkmcnt: staged tile ready; prev buf free
    if (t + 1 < NT) {  // prefetch next tile into other buffer
      if (wid < 4) GLOAD_LDS(ksrc + (size_t)(t + 1) * 32 * HD, &kbuf[cur ^ 1][wid * 512]);
      else         GLOAD_LDS(vsrc + (t + 1) * 32,              &vbuf[cur ^ 1][(wid - 4) * 512]);
    }
    const bf16_t* kb = kbuf[cur];
    const bf16_t* vb = vbuf[cur];
    int x0 = lr & 7;
    bf16x8 k00 = ldb8(kb + lr * 64 + ((lk ^ x0) * 8));
    bf16x8 k01 = ldb8(kb + lr * 64 + (((lk + 4) ^ x0) * 8));
    bf16x8 k10 = ldb8(kb + (16 + lr) * 64 + ((lk ^ x0) * 8));
    bf16x8 k11 = ldb8(kb + (16 + lr) * 64 + (((lk + 4) ^ x0) * 8));
    f32x4 s0 = {}, s1 = {};
    s0 = MFMA(k00, aq0, s0);               // S^T[key][q]
    s0 = MFMA(k01, aq1, s0);
    s1 = MFMA(k10, aq0, s1);
    s1 = MFMA(k11, aq1, s1);
    // lane holds keys {lk*4+r, 16+lk*4+r} for query lr
    float pm = fmaxf(fmaxf(fmaxf(s0[0], s0[1]), fmaxf(s0[2], s0[3])),
                     fmaxf(fmaxf(s1[0], s1[1]), fmaxf(s1[2], s1[3])));
    pm = fmaxf(pm, __shfl_xor(pm, 16));
    pm = fmaxf(pm, __shfl_xor(pm, 32));
    if (!__all(pm <= m_r)) {
      float mn = fmaxf(m_r, pm);
      float sf = exp2f((m_r - mn) * lam);
      m_r = mn;
      l_r *= sf;
#pragma unroll
      for (int dt = 0; dt < 4; dt++) acc[dt] = acc[dt] * sf;
    }
    float mnl = m_r * lam;
    f32x4 p0, p1;
#pragma unroll
    for (int r = 0; r < 4; r++) {
      p0[r] = exp2f(s0[r] * lam - mnl);
      p1[r] = exp2f(s1[r] * lam - mnl);
    }
    float rs = ((p0[0] + p0[1]) + (p0[2] + p0[3])) + ((p1[0] + p1[1]) + (p1[2] + p1[3]));
    rs += __shfl_xor(rs, 16);
    rs += __shfl_xor(rs, 32);
    l_r += rs;
    bf16x4 w0, w1;
#pragma unroll
    for (int r = 0; r < 4; r++) { w0[r] = (__bf16)p0[r]; w1[r] = (__bf16)p1[r]; }
    *reinterpret_cast<bf16x4*>(myp + lr * 40 + lk * 4) = w0;        // P[q=lr][keys lk*4..]
    *reinterpret_cast<bf16x4*>(myp + lr * 40 + 16 + lk * 4) = w1;   // P[q=lr][keys 16+lk*4..]
    bf16x8 pa = ldb8(myp + lr * 40 + lk * 8);                       // B-frag: P[q=lr][lk*8+j]
    int y0 = (lr >> 1) & 3;
#pragma unroll
    for (int dt = 0; dt < 4; dt++) {
      bf16x8 vf = ldb8(vb + (dt * 16 + lr) * 32 + ((lk ^ y0) * 8));
      acc[dt] = MFMA(vf, pa, acc[dt]);    // O^T[d][q]
    }
    cur ^= 1;
  }
  float inv_l = 1.f / l_r;
  bf16_t* obase = Opart + (((size_t)z * NH + h) * Nn + q0 + lr) * HD + lk * 4;
#pragma unroll
  for (int dt = 0; dt < 4; dt++) {
    bf16x4 ov;
#pragma unroll
    for (int r = 0; r < 4; r++) ov[r] = (__bf16)(acc[dt][r] * inv_l);
    *reinterpret_cast<bf16x4*>(obase + dt * 16) = ov;
  }
  if (lk == 0) {
    float2 mlv = make_float2(m_r, l_r);
    *reinterpret_cast<float2*>(ml + (((size_t)z * NH + h) * Nn + q0 + lr) * 2) = mlv;
  }
}

// ---------------- merge split-K partials -> At[b][n][c] bf16 ----------------
__global__ __launch_bounds__(256) void attn_merge(const bf16_t* __restrict__ Opart,
    const float* __restrict__ ml, bf16_t* __restrict__ At) {
  int gid = blockIdx.x * 256 + threadIdx.x;
  int d0 = (gid & 7) * 8;
  int q = (gid >> 3) & (Nn - 1);
  int h = (gid >> 15) & (NH - 1);
  int b = gid >> 17;
  const float lam = 0.0625f * 1.44269504088896f;
  size_t zi0 = ((size_t)(0 * Bz + b) * NH + h) * Nn + q;
  size_t zi1 = ((size_t)(1 * Bz + b) * NH + h) * Nn + q;
  float m0 = ml[zi0 * 2], l0 = ml[zi0 * 2 + 1];
  float m1 = ml[zi1 * 2], l1 = ml[zi1 * 2 + 1];
  float M = fmaxf(m0, m1);
  float w0 = l0 * exp2f((m0 - M) * lam);
  float w1 = l1 * exp2f((m1 - M) * lam);
  float invL = 1.f / (w0 + w1);
  bf16x8 a0 = ldb8(Opart + zi0 * HD + d0);
  bf16x8 a1 = ldb8(Opart + zi1 * HD + d0);
  bf16x8 ov;
#pragma unroll
  for (int r = 0; r < 8; r++)
    ov[r] = (__bf16)(((float)a0[r] * w0 + (float)a1[r] * w1) * invL);
  *reinterpret_cast<bf16x8*>(At + ((size_t)b * Nn + q) * Cc + h * HD + d0) = ov;
}

// ---------------- out GEMM + bias + residual ----------------
__global__ __launch_bounds__(256) void out_gemm(const bf16_t* __restrict__ At,
    const bf16_t* __restrict__ w, const float* __restrict__ bo,
    const float* __restrict__ x, float* __restrict__ out) {
  int b = blockIdx.z;
  int o0 = blockIdx.y * 64;
  int n0 = blockIdx.x * 64;
  int wid = threadIdx.x >> 6;
  int lane = threadIdx.x & 63;
  int lr = lane & 15, lk = lane >> 4;
  const bf16_t* aa = At + ((size_t)b * Nn + n0 + wid * 16 + lr) * Cc + lk * 8;
  const bf16_t* bw = w + (size_t)(o0 + lr) * Cc + lk * 8;
  f32x4 acc[4] = {};
#pragma unroll
  for (int kk = 0; kk < Cc / 32; kk++) {
    bf16x8 a = ldb8(aa + kk * 32);
#pragma unroll
    for (int os = 0; os < 4; os++) {
      bf16x8 bb = ldb8(bw + (size_t)os * 16 * Cc + kk * 32);
      acc[os] = MFMA(a, bb, acc[os]);
    }
  }
  __shared__ float t[64][68];
#pragma unroll
  for (int os = 0; os < 4; os++)
#pragma unroll
    for (int r = 0; r < 4; r++)
      t[wid * 16 + lk * 4 + r][os * 16 + lr] = acc[os][r];
  __syncthreads();
  int orow = threadIdx.x >> 2;
  int nch = (threadIdx.x & 3) * 16;
  size_t base = ((size_t)b * Cc + o0 + orow) * Nn + n0 + nch;
  float bv = bo[o0 + orow];
#pragma unroll
  for (int j = 0; j < 16; j++)
    out[base + j] = t[nch + j][orow] + bv + x[base + j];
}

extern "C" void kernel_launch(void* const* d_in, const int* in_sizes, int n_in,
                              void* d_out, int out_size, void* d_ws, size_t ws_size,
                              hipStream_t stream) {
  const float* x = (const float*)d_in[0];
  const float* gn_scale = (const float*)d_in[1];
  const float* gn_bias = (const float*)d_in[2];
  const float* w_qkv = (const float*)d_in[3];
  const float* w_out = (const float*)d_in[4];
  const float* b_out = (const float*)d_in[5];
  float* out = (float*)d_out;
  char* ws = (char*)d_ws;

  // Workspace layout (peak ~20.6 MiB) — same as R3 (proven):
  float* stats4 = (float*)(ws + 0);
  bf16_t* wout_b = (bf16_t*)(ws + 4096);
  bf16_t* Qt = (bf16_t*)(ws + 139264);
  bf16_t* At = (bf16_t*)(ws + 139264);          // aliases Qt after attn
  bf16_t* Kt = (bf16_t*)(ws + 4333568);
  bf16_t* V = (bf16_t*)(ws + 8527872);
  bf16_t* wqkv_b = (bf16_t*)(ws + 12722176);    // dead after qkv_gemm
  bf16_t* normt = (bf16_t*)(ws + 13115392);     // dead after qkv_gemm
  bf16_t* Opart = (bf16_t*)(ws + 12722176);     // live from attn_kern (8 MB)
  float* ml = (float*)(ws + 21110784);          // 512 KB

  conv_w<<<768, 256, 0, stream>>>(w_qkv, w_out, wqkv_b, wout_b);
  gn_reduce<<<dim3(Bz * NG, GNPART), 256, 0, stream>>>(x, stats4);
  gn_apply<<<dim3(Nn / 64, Cc / 64, Bz), 256, 0, stream>>>(x, stats4, gn_scale, gn_bias, normt);
  qkv_gemm<<<dim3(Nn / 64, 12, Bz), 256, 0, stream>>>(normt, wqkv_b, Qt, Kt, V);
  attn_kern<<<dim3(Nn / 128, NH, Bz * NSPLIT), 512, 0, stream>>>(Qt, Kt, V, Opart, ml);
  attn_merge<<<Bz * NH * Nn * HD / 8 / 256, 256, 0, stream>>>(Opart, ml, At);
  out_gemm<<<dim3(Nn / 64, Cc / 64, Bz), 256, 0, stream>>>(At, wout_b, b_out, x, out);
}

// Round 5
// 128.150 us; speedup vs baseline: 2.3652x; 1.1283x over previous
//
#include <hip/hip_runtime.h>
#include <hip/hip_bf16.h>

#define Bz 2
#define Cc 256
#define Nn 4096
#define NH 4
#define HD 64
#define NG 32
#define CPG 8
#define EPSv 1e-5f
#define NSPLIT 2   // key-dim splits for attention
#define GNPART 4   // partial blocks per group in gn_reduce

typedef __bf16 bf16x8 __attribute__((ext_vector_type(8)));
typedef __bf16 bf16x4 __attribute__((ext_vector_type(4)));
typedef float f32x4 __attribute__((ext_vector_type(4)));
using bf16_t = __hip_bfloat16;

#define MFMA(a, b, c) __builtin_amdgcn_mfma_f32_16x16x32_bf16(a, b, c, 0, 0, 0)

#define GLOAD_LDS(g, l)                                                        \
  __builtin_amdgcn_global_load_lds(                                            \
      (const __attribute__((address_space(1))) void*)(g),                      \
      (__attribute__((address_space(3))) void*)(l), 16, 0, 0)

__device__ __forceinline__ bf16x8 ldb8(const bf16_t* p) {
  return *reinterpret_cast<const bf16x8*>(p);
}

// ---------------- GroupNorm: partial sums per (b,g,quarter) ----------------
__global__ __launch_bounds__(256) void gn_reduce(const float* __restrict__ x,
                                                 float* __restrict__ stats4) {
  int bg = blockIdx.x;
  int part = blockIdx.y;
  const float4* p4 = reinterpret_cast<const float4*>(
      x + (size_t)bg * (CPG * Nn) + (size_t)part * (CPG * Nn / GNPART));
  float s = 0.f, ss = 0.f;
  for (int i = threadIdx.x; i < CPG * Nn / GNPART / 4; i += 256) {
    float4 v = p4[i];
    s += v.x + v.y + v.z + v.w;
    ss += v.x * v.x + v.y * v.y + v.z * v.z + v.w * v.w;
  }
#pragma unroll
  for (int off = 32; off > 0; off >>= 1) {
    s += __shfl_down(s, off);
    ss += __shfl_down(ss, off);
  }
  __shared__ float ps[4], pss[4];
  int wid = threadIdx.x >> 6;
  if ((threadIdx.x & 63) == 0) { ps[wid] = s; pss[wid] = ss; }
  __syncthreads();
  if (threadIdx.x == 0) {
    stats4[(bg * GNPART + part) * 2] = ps[0] + ps[1] + ps[2] + ps[3];
    stats4[(bg * GNPART + part) * 2 + 1] = pss[0] + pss[1] + pss[2] + pss[3];
  }
}

// ------ GroupNorm apply -> norm_t[b][n][c] bf16, coalesced both sides ------
__global__ __launch_bounds__(256) void gn_apply(const float* __restrict__ x,
    const float* __restrict__ stats4, const float* __restrict__ sc,
    const float* __restrict__ bi, bf16_t* __restrict__ normt) {
  int b = blockIdx.z, c0 = blockIdx.y * 64, n0 = blockIdx.x * 64;
  __shared__ __align__(16) __bf16 t[64][72];
  int cx = threadIdx.x & 15, cy0 = threadIdx.x >> 4;
  const float inv = 1.f / (float)(CPG * Nn);
#pragma unroll
  for (int j = 0; j < 4; j++) {
    int c = c0 + cy0 + j * 16;
    int bg = b * NG + (c >> 3);
    float S = stats4[bg * 8] + stats4[bg * 8 + 2] + stats4[bg * 8 + 4] + stats4[bg * 8 + 6];
    float SS = stats4[bg * 8 + 1] + stats4[bg * 8 + 3] + stats4[bg * 8 + 5] + stats4[bg * 8 + 7];
    float mean = S * inv;
    float rstd = rsqrtf(SS * inv - mean * mean + EPSv);
    float a = rstd * sc[c];
    float bb = bi[c] - mean * a;
    float4 v = *reinterpret_cast<const float4*>(x + ((size_t)b * Cc + c) * Nn + n0 + cx * 4);
    bf16x4 w;
    w[0] = (__bf16)(v.x * a + bb); w[1] = (__bf16)(v.y * a + bb);
    w[2] = (__bf16)(v.z * a + bb); w[3] = (__bf16)(v.w * a + bb);
    *reinterpret_cast<bf16x4*>(&t[cy0 + j * 16][cx * 4]) = w;
  }
  __syncthreads();
  int ny = threadIdx.x >> 2, ch0 = threadIdx.x & 3;
#pragma unroll
  for (int j = 0; j < 2; j++) {
    int ch = ch0 + j * 4;
    bf16x8 o;
#pragma unroll
    for (int jj = 0; jj < 8; jj++) o[jj] = t[ch * 8 + jj][ny];
    *reinterpret_cast<bf16x8*>(normt + ((size_t)b * Nn + n0 + ny) * Cc + c0 + ch * 8) = o;
  }
}

// ---------------- weight fp32 -> bf16 ----------------
__global__ __launch_bounds__(256) void conv_w(const float* __restrict__ wq,
    const float* __restrict__ wo, bf16_t* __restrict__ wqb,
    bf16_t* __restrict__ wob) {
  int i = blockIdx.x * 256 + threadIdx.x;
  if (i < 768 * Cc) wqb[i] = __float2bfloat16(wq[i]);
  if (i < Cc * Cc) wob[i] = __float2bfloat16(wo[i]);
}

// ---------------- QKV GEMM ----------------
__global__ __launch_bounds__(256) void qkv_gemm(const bf16_t* __restrict__ normt,
    const bf16_t* __restrict__ w, bf16_t* __restrict__ Qt,
    bf16_t* __restrict__ Kt, bf16_t* __restrict__ V) {
  int b = blockIdx.z;
  int o0 = blockIdx.y * 64;
  int n0 = blockIdx.x * 64;
  int wid = threadIdx.x >> 6;
  int lane = threadIdx.x & 63;
  int lr = lane & 15, lk = lane >> 4;
  const bf16_t* an = normt + ((size_t)b * Nn + n0 + wid * 16 + lr) * Cc + lk * 8;
  const bf16_t* bw = w + (size_t)(o0 + lr) * Cc + lk * 8;
  f32x4 acc[4] = {};
#pragma unroll
  for (int kk = 0; kk < Cc / 32; kk++) {
    bf16x8 a = ldb8(an + kk * 32);
#pragma unroll
    for (int os = 0; os < 4; os++) {
      bf16x8 bb = ldb8(bw + (size_t)os * 16 * Cc + kk * 32);
      acc[os] = MFMA(a, bb, acc[os]);
    }
  }
  int h = o0 / 192;
  int part = (o0 % 192) / 64;
  if (part < 2) {
    bf16_t* dst = (part == 0 ? Qt : Kt) + (size_t)(b * NH + h) * Nn * HD;
#pragma unroll
    for (int os = 0; os < 4; os++)
#pragma unroll
      for (int r = 0; r < 4; r++) {
        int n = n0 + wid * 16 + lk * 4 + r;
        int d = os * 16 + lr;
        dst[(size_t)n * HD + d] = __float2bfloat16(acc[os][r]);
      }
  } else {
    __shared__ float t[64][68];
#pragma unroll
    for (int os = 0; os < 4; os++)
#pragma unroll
      for (int r = 0; r < 4; r++)
        t[wid * 16 + lk * 4 + r][os * 16 + lr] = acc[os][r];
    __syncthreads();
    bf16_t* dst = V + (size_t)(b * NH + h) * HD * Nn;
    int d = threadIdx.x >> 2;
    int nch = (threadIdx.x & 3) * 16;
#pragma unroll
    for (int j = 0; j < 16; j++)
      dst[(size_t)d * Nn + n0 + nch + j] = __float2bfloat16(t[nch + j][d]);
  }
}

// ---- Flash attention v2: 8 waves, KVBLK=64, per-lane deferred softmax ----
// K_lds/V_lds [64][64] bf16 (128B rows), 16B-unit swizzle c^=(row&7); linear
// DMA dest + inverse-swizzled per-lane GLOBAL source (rule #21).
// Swapped QK^T: lane (lr,lk) holds S^T for query lr, keys {16m+4lk+r}.
__global__ __launch_bounds__(512, 4) void attn_kern(const bf16_t* __restrict__ Qt,
    const bf16_t* __restrict__ Kt, const bf16_t* __restrict__ V,
    bf16_t* __restrict__ Opart, float* __restrict__ ml) {
  int z = blockIdx.z;          // z = split*Bz + b
  int b = z & 1, sp = z >> 1;
  int h = blockIdx.y;
  int wid = threadIdx.x >> 6, lane = threadIdx.x & 63;
  int lr = lane & 15, lk = lane >> 4;
  int q0 = blockIdx.x * 128 + wid * 16;
  size_t bh = (size_t)(b * NH + h);
  const bf16_t* qp = Qt + (bh * Nn + q0 + lr) * HD + lk * 8;
  bf16x8 aq0 = ldb8(qp), aq1 = ldb8(qp + 32);
  const bf16_t* kglob = Kt + bh * Nn * HD;
  const bf16_t* vglob = V + bh * HD * Nn;
  int kbeg = sp * (Nn / NSPLIT);

  __shared__ __align__(16) bf16_t kbuf[2][64 * 64];   // 16 KB
  __shared__ __align__(16) bf16_t vbuf[2][64 * 64];   // 16 KB
  __shared__ __align__(16) bf16_t plds[8][16 * 72];   // 18 KB (row stride 144B)
  bf16_t* myp = plds[wid];

  // staging: 16B-unit u = (wid&3)*64+lane in [0,256); round2 adds 256 (row+32)
  int su = (wid & 3) * 64 + lane;
  int srow = su >> 3, sc = su & 7;
  int swz = (sc ^ (srow & 7)) * 8;
  const bf16_t* ksrc = kglob + (size_t)(kbeg + srow) * HD + swz;   // waves 0-3
  const bf16_t* vsrc = vglob + (size_t)srow * Nn + kbeg + swz;     // waves 4-7

  f32x4 acc[4] = {};
  float m_r = -1e30f, l_r = 0.f;
  const float lam = 0.0625f * 1.44269504088896f;  // (1/sqrt(C)) * log2(e)
  const int NT = (Nn / NSPLIT) / 64;              // 32 (even)

#define STAGE(buf, t)                                                          \
  do {                                                                         \
    if (wid < 4) {                                                             \
      GLOAD_LDS(ksrc + (size_t)(t) * 64 * HD, &kbuf[buf][(wid & 3) * 512]);    \
      GLOAD_LDS(ksrc + (size_t)(t) * 64 * HD + 32 * HD,                        \
                &kbuf[buf][2048 + (wid & 3) * 512]);                           \
    } else {                                                                   \
      GLOAD_LDS(vsrc + (size_t)(t) * 64, &vbuf[buf][(wid & 3) * 512]);         \
      GLOAD_LDS(vsrc + (size_t)(t) * 64 + (size_t)32 * Nn,                     \
                &vbuf[buf][2048 + (wid & 3) * 512]);                           \
    }                                                                          \
  } while (0)

  // frag addr within [64][64] tile: row=16*m+lr, 16B-unit c=4*kk+lk, swizzled
#define FADDR(m, kk) ((16 * (m) + lr) * 64 + (((4 * (kk) + lk) ^ (lr & 7)) * 8))

#define STEP(t, buf)                                                           \
  do {                                                                         \
    __syncthreads();                                                           \
    STAGE(buf ^ 1, (t) + 1);                                                   \
    const bf16_t* kb = kbuf[buf];                                              \
    const bf16_t* vb = vbuf[buf];                                              \
    f32x4 s0 = {}, s1 = {}, s2 = {}, s3 = {};                                  \
    __builtin_amdgcn_s_setprio(1);                                             \
    s0 = MFMA(ldb8(kb + FADDR(0, 0)), aq0, s0);                                \
    s0 = MFMA(ldb8(kb + FADDR(0, 1)), aq1, s0);                                \
    s1 = MFMA(ldb8(kb + FADDR(1, 0)), aq0, s1);                                \
    s1 = MFMA(ldb8(kb + FADDR(1, 1)), aq1, s1);                                \
    s2 = MFMA(ldb8(kb + FADDR(2, 0)), aq0, s2);                                \
    s2 = MFMA(ldb8(kb + FADDR(2, 1)), aq1, s2);                                \
    s3 = MFMA(ldb8(kb + FADDR(3, 0)), aq0, s3);                                \
    s3 = MFMA(ldb8(kb + FADDR(3, 1)), aq1, s3);                                \
    __builtin_amdgcn_s_setprio(0);                                             \
    float pm = fmaxf(fmaxf(fmaxf(s0[0], s0[1]), fmaxf(s0[2], s0[3])),          \
                     fmaxf(fmaxf(s1[0], s1[1]), fmaxf(s1[2], s1[3])));         \
    pm = fmaxf(pm, fmaxf(fmaxf(fmaxf(s2[0], s2[1]), fmaxf(s2[2], s2[3])),      \
                         fmaxf(fmaxf(s3[0], s3[1]), fmaxf(s3[2], s3[3]))));    \
    if (!__all(pm <= m_r + 64.f)) {       /* rare: new max beyond defer bound */\
      float pw = fmaxf(pm, __shfl_xor(pm, 16));                                \
      pw = fmaxf(pw, __shfl_xor(pw, 32));                                      \
      float mn = fmaxf(m_r, pw);                                               \
      float sf = exp2f((m_r - mn) * lam);                                      \
      m_r = mn;                                                                \
      l_r *= sf;                                                               \
      acc[0] = acc[0] * sf; acc[1] = acc[1] * sf;                              \
      acc[2] = acc[2] * sf; acc[3] = acc[3] * sf;                              \
    }                                                                          \
    float mnl = m_r * lam;                                                     \
    f32x4 p0, p1, p2, p3;                                                      \
    _Pragma("unroll") for (int r = 0; r < 4; r++) {                            \
      p0[r] = exp2f(s0[r] * lam - mnl);                                        \
      p1[r] = exp2f(s1[r] * lam - mnl);                                        \
      p2[r] = exp2f(s2[r] * lam - mnl);                                        \
      p3[r] = exp2f(s3[r] * lam - mnl);                                        \
    }                                                                          \
    f32x4 ps = (p0 + p1) + (p2 + p3);                                          \
    l_r += (ps[0] + ps[1]) + (ps[2] + ps[3]);                                  \
    bf16x4 w0, w1, w2, w3;                                                     \
    _Pragma("unroll") for (int r = 0; r < 4; r++) {                            \
      w0[r] = (__bf16)p0[r]; w1[r] = (__bf16)p1[r];                            \
      w2[r] = (__bf16)p2[r]; w3[r] = (__bf16)p3[r];                            \
    }                                                                          \
    *reinterpret_cast<bf16x4*>(myp + lr * 72 + lk * 4) = w0;                   \
    *reinterpret_cast<bf16x4*>(myp + lr * 72 + 16 + lk * 4) = w1;              \
    *reinterpret_cast<bf16x4*>(myp + lr * 72 + 32 + lk * 4) = w2;              \
    *reinterpret_cast<bf16x4*>(myp + lr * 72 + 48 + lk * 4) = w3;              \
    bf16x8 pa0 = ldb8(myp + lr * 72 + lk * 8);                                 \
    bf16x8 pa1 = ldb8(myp + lr * 72 + 32 + lk * 8);                            \
    __builtin_amdgcn_s_setprio(1);                                             \
    acc[0] = MFMA(ldb8(vb + FADDR(0, 0)), pa0, acc[0]);                        \
    acc[0] = MFMA(ldb8(vb + FADDR(0, 1)), pa1, acc[0]);                        \
    acc[1] = MFMA(ldb8(vb + FADDR(1, 0)), pa0, acc[1]);                        \
    acc[1] = MFMA(ldb8(vb + FADDR(1, 1)), pa1, acc[1]);                        \
    acc[2] = MFMA(ldb8(vb + FADDR(2, 0)), pa0, acc[2]);                        \
    acc[2] = MFMA(ldb8(vb + FADDR(2, 1)), pa1, acc[2]);                        \
    acc[3] = MFMA(ldb8(vb + FADDR(3, 0)), pa0, acc[3]);                        \
    acc[3] = MFMA(ldb8(vb + FADDR(3, 1)), pa1, acc[3]);                        \
    __builtin_amdgcn_s_setprio(0);                                             \
  } while (0)

  STAGE(0, 0);  // prologue
  for (int t = 0; t < NT; t += 2) {
    STEP(t, 0);
    STEP(t + 1, 1);
  }
#undef STEP
#undef STAGE
#undef FADDR

  // cross-lane l reduce (m is already query-uniform by construction)
  l_r += __shfl_xor(l_r, 16);
  l_r += __shfl_xor(l_r, 32);
  float inv_l = 1.f / l_r;
  bf16_t* obase = Opart + (((size_t)z * NH + h) * Nn + q0 + lr) * HD + lk * 4;
#pragma unroll
  for (int dt = 0; dt < 4; dt++) {
    bf16x4 ov;
#pragma unroll
    for (int r = 0; r < 4; r++) ov[r] = (__bf16)(acc[dt][r] * inv_l);
    *reinterpret_cast<bf16x4*>(obase + dt * 16) = ov;
  }
  if (lk == 0) {
    float2 mlv = make_float2(m_r, l_r);
    *reinterpret_cast<float2*>(ml + (((size_t)z * NH + h) * Nn + q0 + lr) * 2) = mlv;
  }
}

// ---------------- merge split-K partials -> At[b][n][c] bf16 ----------------
__global__ __launch_bounds__(256) void attn_merge(const bf16_t* __restrict__ Opart,
    const float* __restrict__ ml, bf16_t* __restrict__ At) {
  int gid = blockIdx.x * 256 + threadIdx.x;
  int d0 = (gid & 7) * 8;
  int q = (gid >> 3) & (Nn - 1);
  int h = (gid >> 15) & (NH - 1);
  int b = gid >> 17;
  const float lam = 0.0625f * 1.44269504088896f;
  size_t zi0 = ((size_t)(0 * Bz + b) * NH + h) * Nn + q;
  size_t zi1 = ((size_t)(1 * Bz + b) * NH + h) * Nn + q;
  float m0 = ml[zi0 * 2], l0 = ml[zi0 * 2 + 1];
  float m1 = ml[zi1 * 2], l1 = ml[zi1 * 2 + 1];
  float M = fmaxf(m0, m1);
  float w0 = l0 * exp2f((m0 - M) * lam);
  float w1 = l1 * exp2f((m1 - M) * lam);
  float invL = 1.f / (w0 + w1);
  bf16x8 a0 = ldb8(Opart + zi0 * HD + d0);
  bf16x8 a1 = ldb8(Opart + zi1 * HD + d0);
  bf16x8 ov;
#pragma unroll
  for (int r = 0; r < 8; r++)
    ov[r] = (__bf16)(((float)a0[r] * w0 + (float)a1[r] * w1) * invL);
  *reinterpret_cast<bf16x8*>(At + ((size_t)b * Nn + q) * Cc + h * HD + d0) = ov;
}

// ---------------- out GEMM + bias + residual ----------------
__global__ __launch_bounds__(256) void out_gemm(const bf16_t* __restrict__ At,
    const bf16_t* __restrict__ w, const float* __restrict__ bo,
    const float* __restrict__ x, float* __restrict__ out) {
  int b = blockIdx.z;
  int o0 = blockIdx.y * 64;
  int n0 = blockIdx.x * 64;
  int wid = threadIdx.x >> 6;
  int lane = threadIdx.x & 63;
  int lr = lane & 15, lk = lane >> 4;
  const bf16_t* aa = At + ((size_t)b * Nn + n0 + wid * 16 + lr) * Cc + lk * 8;
  const bf16_t* bw = w + (size_t)(o0 + lr) * Cc + lk * 8;
  f32x4 acc[4] = {};
#pragma unroll
  for (int kk = 0; kk < Cc / 32; kk++) {
    bf16x8 a = ldb8(aa + kk * 32);
#pragma unroll
    for (int os = 0; os < 4; os++) {
      bf16x8 bb = ldb8(bw + (size_t)os * 16 * Cc + kk * 32);
      acc[os] = MFMA(a, bb, acc[os]);
    }
  }
  __shared__ float t[64][68];
#pragma unroll
  for (int os = 0; os < 4; os++)
#pragma unroll
    for (int r = 0; r < 4; r++)
      t[wid * 16 + lk * 4 + r][os * 16 + lr] = acc[os][r];
  __syncthreads();
  int orow = threadIdx.x >> 2;
  int nch = (threadIdx.x & 3) * 16;
  size_t base = ((size_t)b * Cc + o0 + orow) * Nn + n0 + nch;
  float bv = bo[o0 + orow];
#pragma unroll
  for (int j = 0; j < 16; j++)
    out[base + j] = t[nch + j][orow] + bv + x[base + j];
}

extern "C" void kernel_launch(void* const* d_in, const int* in_sizes, int n_in,
                              void* d_out, int out_size, void* d_ws, size_t ws_size,
                              hipStream_t stream) {
  const float* x = (const float*)d_in[0];
  const float* gn_scale = (const float*)d_in[1];
  const float* gn_bias = (const float*)d_in[2];
  const float* w_qkv = (const float*)d_in[3];
  const float* w_out = (const float*)d_in[4];
  const float* b_out = (const float*)d_in[5];
  float* out = (float*)d_out;
  char* ws = (char*)d_ws;

  // Workspace layout (peak ~20.6 MiB) — same as R3/R4 (proven):
  float* stats4 = (float*)(ws + 0);
  bf16_t* wout_b = (bf16_t*)(ws + 4096);
  bf16_t* Qt = (bf16_t*)(ws + 139264);
  bf16_t* At = (bf16_t*)(ws + 139264);          // aliases Qt after attn
  bf16_t* Kt = (bf16_t*)(ws + 4333568);
  bf16_t* V = (bf16_t*)(ws + 8527872);
  bf16_t* wqkv_b = (bf16_t*)(ws + 12722176);    // dead after qkv_gemm
  bf16_t* normt = (bf16_t*)(ws + 13115392);     // dead after qkv_gemm
  bf16_t* Opart = (bf16_t*)(ws + 12722176);     // live from attn_kern (8 MB)
  float* ml = (float*)(ws + 21110784);          // 512 KB

  conv_w<<<768, 256, 0, stream>>>(w_qkv, w_out, wqkv_b, wout_b);
  gn_reduce<<<dim3(Bz * NG, GNPART), 256, 0, stream>>>(x, stats4);
  gn_apply<<<dim3(Nn / 64, Cc / 64, Bz), 256, 0, stream>>>(x, stats4, gn_scale, gn_bias, normt);
  qkv_gemm<<<dim3(Nn / 64, 12, Bz), 256, 0, stream>>>(normt, wqkv_b, Qt, Kt, V);
  attn_kern<<<dim3(Nn / 128, NH, Bz * NSPLIT), 512, 0, stream>>>(Qt, Kt, V, Opart, ml);
  attn_merge<<<Bz * NH * Nn * HD / 8 / 256, 256, 0, stream>>>(Opart, ml, At);
  out_gemm<<<dim3(Nn / 64, Cc / 64, Bz), 256, 0, stream>>>(At, wout_b, b_out, x, out);
}

// Round 7
// 90.730 us; speedup vs baseline: 3.3407x; 1.4124x over previous
//
#include <hip/hip_runtime.h>
#include <hip/hip_bf16.h>

#define Bz 2
#define Cc 256
#define Nn 4096
#define NH 4
#define HD 64
#define NG 32
#define CPG 8
#define EPSv 1e-5f
#define NSPLIT 4   // key-dim splits for attention
#define GNPART 4   // partial blocks per group in gn_reduce

typedef __bf16 bf16x8 __attribute__((ext_vector_type(8)));
typedef __bf16 bf16x4 __attribute__((ext_vector_type(4)));
typedef float f32x4 __attribute__((ext_vector_type(4)));
using bf16_t = __hip_bfloat16;

#define MFMA(a, b, c) __builtin_amdgcn_mfma_f32_16x16x32_bf16(a, b, c, 0, 0, 0)

#define GLOAD_LDS(g, l)                                                        \
  __builtin_amdgcn_global_load_lds(                                            \
      (const __attribute__((address_space(1))) void*)(g),                      \
      (__attribute__((address_space(3))) void*)(l), 16, 0, 0)

// raw v_exp_f32 (1-ulp exp2): args here are bounded above by the defer
// threshold and large-negative args flushing to 0 is the desired softmax
// behavior, so the libm denormal-fixup expansion is pure overhead.
#define EXP2(x)                                                                \
  ({ float _r, _x = (x); asm("v_exp_f32 %0, %1" : "=v"(_r) : "v"(_x)); _r; })

__device__ __forceinline__ bf16x8 ldb8(const bf16_t* p) {
  return *reinterpret_cast<const bf16x8*>(p);
}

// ---------------- GroupNorm: partial sums per (b,g,quarter) ----------------
__global__ __launch_bounds__(256) void gn_reduce(const float* __restrict__ x,
                                                 float* __restrict__ stats4) {
  int bg = blockIdx.x;
  int part = blockIdx.y;
  const float4* p4 = reinterpret_cast<const float4*>(
      x + (size_t)bg * (CPG * Nn) + (size_t)part * (CPG * Nn / GNPART));
  float s = 0.f, ss = 0.f;
  for (int i = threadIdx.x; i < CPG * Nn / GNPART / 4; i += 256) {
    float4 v = p4[i];
    s += v.x + v.y + v.z + v.w;
    ss += v.x * v.x + v.y * v.y + v.z * v.z + v.w * v.w;
  }
#pragma unroll
  for (int off = 32; off > 0; off >>= 1) {
    s += __shfl_down(s, off);
    ss += __shfl_down(ss, off);
  }
  __shared__ float ps[4], pss[4];
  int wid = threadIdx.x >> 6;
  if ((threadIdx.x & 63) == 0) { ps[wid] = s; pss[wid] = ss; }
  __syncthreads();
  if (threadIdx.x == 0) {
    stats4[(bg * GNPART + part) * 2] = ps[0] + ps[1] + ps[2] + ps[3];
    stats4[(bg * GNPART + part) * 2 + 1] = pss[0] + pss[1] + pss[2] + pss[3];
  }
}

// ------ GroupNorm apply -> norm_t[b][n][c] bf16, coalesced both sides ------
__global__ __launch_bounds__(256) void gn_apply(const float* __restrict__ x,
    const float* __restrict__ stats4, const float* __restrict__ sc,
    const float* __restrict__ bi, bf16_t* __restrict__ normt) {
  int b = blockIdx.z, c0 = blockIdx.y * 64, n0 = blockIdx.x * 64;
  __shared__ __align__(16) __bf16 t[64][72];
  int cx = threadIdx.x & 15, cy0 = threadIdx.x >> 4;
  const float inv = 1.f / (float)(CPG * Nn);
#pragma unroll
  for (int j = 0; j < 4; j++) {
    int c = c0 + cy0 + j * 16;
    int bg = b * NG + (c >> 3);
    float S = stats4[bg * 8] + stats4[bg * 8 + 2] + stats4[bg * 8 + 4] + stats4[bg * 8 + 6];
    float SS = stats4[bg * 8 + 1] + stats4[bg * 8 + 3] + stats4[bg * 8 + 5] + stats4[bg * 8 + 7];
    float mean = S * inv;
    float rstd = rsqrtf(SS * inv - mean * mean + EPSv);
    float a = rstd * sc[c];
    float bb = bi[c] - mean * a;
    float4 v = *reinterpret_cast<const float4*>(x + ((size_t)b * Cc + c) * Nn + n0 + cx * 4);
    bf16x4 w;
    w[0] = (__bf16)(v.x * a + bb); w[1] = (__bf16)(v.y * a + bb);
    w[2] = (__bf16)(v.z * a + bb); w[3] = (__bf16)(v.w * a + bb);
    *reinterpret_cast<bf16x4*>(&t[cy0 + j * 16][cx * 4]) = w;
  }
  __syncthreads();
  int ny = threadIdx.x >> 2, ch0 = threadIdx.x & 3;
#pragma unroll
  for (int j = 0; j < 2; j++) {
    int ch = ch0 + j * 4;
    bf16x8 o;
#pragma unroll
    for (int jj = 0; jj < 8; jj++) o[jj] = t[ch * 8 + jj][ny];
    *reinterpret_cast<bf16x8*>(normt + ((size_t)b * Nn + n0 + ny) * Cc + c0 + ch * 8) = o;
  }
}

// ---------------- weight fp32 -> bf16 ----------------
__global__ __launch_bounds__(256) void conv_w(const float* __restrict__ wq,
    const float* __restrict__ wo, bf16_t* __restrict__ wqb,
    bf16_t* __restrict__ wob) {
  int i = blockIdx.x * 256 + threadIdx.x;
  if (i < 768 * Cc) wqb[i] = __float2bfloat16(wq[i]);
  if (i < Cc * Cc) wob[i] = __float2bfloat16(wo[i]);
}

// ------- QKV GEMM: 8 waves, 128n x 64o tile, LDS-staged swizzled weights -----
// wbuf[64][256] bf16 (512B rows), 16B-unit swizzle cu^=(row&7) via
// inverse-swizzled global source (rule #21). Epilogue restages C through a
// bf16 LDS tile (overlapping wbuf) for b128-coalesced Q/K/V stores.
__global__ __launch_bounds__(512) void qkv_gemm(const bf16_t* __restrict__ normt,
    const bf16_t* __restrict__ w, bf16_t* __restrict__ Qt,
    bf16_t* __restrict__ Kt, bf16_t* __restrict__ V) {
  int b = blockIdx.z;
  int o0 = blockIdx.y * 64;
  int n0 = blockIdx.x * 128;
  int tid = threadIdx.x;
  int wid = tid >> 6, lane = tid & 63;
  int lr = lane & 15, lk = lane >> 4;

  __shared__ __align__(16) char smem[64 * 256 * 2];   // 32 KB
  bf16_t* wbuf = (bf16_t*)smem;
  __bf16* t = (__bf16*)smem;                          // [128][80] bf16, 20 KB

#pragma unroll
  for (int rnd = 0; rnd < 4; rnd++) {
    int u = rnd * 512 + tid;           // 16B unit: row=u>>5, col-unit=u&31
    int row = u >> 5, cu = u & 31;
    int cus = (cu & 24) | ((cu & 7) ^ (row & 7));
    GLOAD_LDS(w + (size_t)(o0 + row) * Cc + cus * 8, &wbuf[u * 8]);
  }
  const bf16_t* an = normt + ((size_t)b * Nn + n0 + wid * 16 + lr) * Cc + lk * 8;
  f32x4 acc[4] = {};
  __syncthreads();                     // vmcnt drained -> wbuf ready
#pragma unroll
  for (int kk = 0; kk < Cc / 32; kk++) {
    bf16x8 a = ldb8(an + kk * 32);
#pragma unroll
    for (int os = 0; os < 4; os++) {
      bf16x8 bb = ldb8(&wbuf[(os * 16 + lr) * Cc + (((kk * 4 + lk) ^ (lr & 7)) * 8)]);
      acc[os] = MFMA(a, bb, acc[os]);
    }
  }
  __syncthreads();                     // all wbuf reads done before t overwrite
#pragma unroll
  for (int os = 0; os < 4; os++)
#pragma unroll
    for (int r = 0; r < 4; r++)
      t[(wid * 16 + lk * 4 + r) * 80 + os * 16 + lr] = (__bf16)acc[os][r];
  __syncthreads();
  int h = o0 / 192;
  int part = (o0 % 192) / 64;
  if (part < 2) {
    bf16_t* dst = (part == 0 ? Qt : Kt) + (size_t)(b * NH + h) * Nn * HD + (size_t)n0 * HD;
    int n = tid >> 2, dch = (tid & 3) * 16;
    bf16x8 o1 = ldb8(reinterpret_cast<const bf16_t*>(&t[n * 80 + dch]));
    bf16x8 o2 = ldb8(reinterpret_cast<const bf16_t*>(&t[n * 80 + dch + 8]));
    *reinterpret_cast<bf16x8*>(dst + (size_t)n * HD + dch) = o1;
    *reinterpret_cast<bf16x8*>(dst + (size_t)n * HD + dch + 8) = o2;
  } else {
    bf16_t* dst = V + (size_t)(b * NH + h) * HD * Nn + n0;
    int d = tid >> 3, nch = (tid & 7) * 16;
    bf16x8 o1, o2;
#pragma unroll
    for (int j = 0; j < 8; j++) {
      o1[j] = t[(nch + j) * 80 + d];
      o2[j] = t[(nch + 8 + j) * 80 + d];
    }
    *reinterpret_cast<bf16x8*>(dst + (size_t)d * Nn + nch) = o1;
    *reinterpret_cast<bf16x8*>(dst + (size_t)d * Nn + nch + 8) = o2;
  }
}

// ---- Flash attention: 8 waves, KVBLK=64, deferred softmax, 4-way key split ----
// K_lds/V_lds [64][64] bf16 (128B rows), 16B-unit swizzle c^=(row&7); linear
// DMA dest + inverse-swizzled per-lane GLOBAL source (rule #21).
// Swapped QK^T: lane (lr,lk) holds S^T for query lr, keys {16m+4lk+r}.
__global__ __launch_bounds__(512, 4) void attn_kern(const bf16_t* __restrict__ Qt,
    const bf16_t* __restrict__ Kt, const bf16_t* __restrict__ V,
    bf16_t* __restrict__ Opart, float* __restrict__ ml) {
  int z = blockIdx.z;          // z = split*Bz + b
  int b = z & 1, sp = z >> 1;
  int h = blockIdx.y;
  int wid = threadIdx.x >> 6, lane = threadIdx.x & 63;
  int lr = lane & 15, lk = lane >> 4;
  int q0 = blockIdx.x * 128 + wid * 16;
  size_t bh = (size_t)(b * NH + h);
  const bf16_t* qp = Qt + (bh * Nn + q0 + lr) * HD + lk * 8;
  bf16x8 aq0 = ldb8(qp), aq1 = ldb8(qp + 32);
  const bf16_t* kglob = Kt + bh * Nn * HD;
  const bf16_t* vglob = V + bh * HD * Nn;
  int kbeg = sp * (Nn / NSPLIT);

  __shared__ __align__(16) bf16_t kbuf[2][64 * 64];   // 16 KB
  __shared__ __align__(16) bf16_t vbuf[2][64 * 64];   // 16 KB
  __shared__ __align__(16) bf16_t plds[8][16 * 72];   // 18 KB (row stride 144B)
  bf16_t* myp = plds[wid];

  // staging: 16B-unit u = (wid&3)*64+lane in [0,256); round2 adds 256 (row+32)
  int su = (wid & 3) * 64 + lane;
  int srow = su >> 3, sc = su & 7;
  int swz = (sc ^ (srow & 7)) * 8;
  const bf16_t* ksrc = kglob + (size_t)(kbeg + srow) * HD + swz;   // waves 0-3
  const bf16_t* vsrc = vglob + (size_t)srow * Nn + kbeg + swz;     // waves 4-7

  f32x4 acc[4] = {};
  float m_r = -1e30f, l_r = 0.f;
  const float lam = 0.0625f * 1.44269504088896f;  // (1/sqrt(C)) * log2(e)
  const int NT = (Nn / NSPLIT) / 64;              // 16 (even)

#define STAGE(buf, t)                                                          \
  do {                                                                         \
    if (wid < 4) {                                                             \
      GLOAD_LDS(ksrc + (size_t)(t) * 64 * HD, &kbuf[buf][(wid & 3) * 512]);    \
      GLOAD_LDS(ksrc + (size_t)(t) * 64 * HD + 32 * HD,                        \
                &kbuf[buf][2048 + (wid & 3) * 512]);                           \
    } else {                                                                   \
      GLOAD_LDS(vsrc + (size_t)(t) * 64, &vbuf[buf][(wid & 3) * 512]);         \
      GLOAD_LDS(vsrc + (size_t)(t) * 64 + (size_t)32 * Nn,                     \
                &vbuf[buf][2048 + (wid & 3) * 512]);                           \
    }                                                                          \
  } while (0)

  // frag addr within [64][64] tile: row=16*m+lr, 16B-unit c=4*kk+lk, swizzled
#define FADDR(m, kk) ((16 * (m) + lr) * 64 + (((4 * (kk) + lk) ^ (lr & 7)) * 8))

#define STEP(t, buf)                                                           \
  do {                                                                         \
    __syncthreads();                                                           \
    STAGE(buf ^ 1, (t) + 1);                                                   \
    const bf16_t* kb = kbuf[buf];                                              \
    const bf16_t* vb = vbuf[buf];                                              \
    f32x4 s0 = {}, s1 = {}, s2 = {}, s3 = {};                                  \
    __builtin_amdgcn_s_setprio(1);                                             \
    s0 = MFMA(ldb8(kb + FADDR(0, 0)), aq0, s0);                                \
    s0 = MFMA(ldb8(kb + FADDR(0, 1)), aq1, s0);                                \
    s1 = MFMA(ldb8(kb + FADDR(1, 0)), aq0, s1);                                \
    s1 = MFMA(ldb8(kb + FADDR(1, 1)), aq1, s1);                                \
    s2 = MFMA(ldb8(kb + FADDR(2, 0)), aq0, s2);                                \
    s2 = MFMA(ldb8(kb + FADDR(2, 1)), aq1, s2);                                \
    s3 = MFMA(ldb8(kb + FADDR(3, 0)), aq0, s3);                                \
    s3 = MFMA(ldb8(kb + FADDR(3, 1)), aq1, s3);                                \
    __builtin_amdgcn_s_setprio(0);                                             \
    float pm = fmaxf(fmaxf(fmaxf(s0[0], s0[1]), fmaxf(s0[2], s0[3])),          \
                     fmaxf(fmaxf(s1[0], s1[1]), fmaxf(s1[2], s1[3])));         \
    pm = fmaxf(pm, fmaxf(fmaxf(fmaxf(s2[0], s2[1]), fmaxf(s2[2], s2[3])),      \
                         fmaxf(fmaxf(s3[0], s3[1]), fmaxf(s3[2], s3[3]))));    \
    if (!__all(pm <= m_r + 64.f)) {       /* rare: new max beyond defer bound */\
      float pw = fmaxf(pm, __shfl_xor(pm, 16));                                \
      pw = fmaxf(pw, __shfl_xor(pw, 32));                                      \
      float mn = fmaxf(m_r, pw);                                               \
      float sf = EXP2((m_r - mn) * lam);                                       \
      m_r = mn;                                                                \
      l_r *= sf;                                                               \
      acc[0] = acc[0] * sf; acc[1] = acc[1] * sf;                              \
      acc[2] = acc[2] * sf; acc[3] = acc[3] * sf;                              \
    }                                                                          \
    float mnl = m_r * lam;                                                     \
    f32x4 p0, p1, p2, p3;                                                      \
    _Pragma("unroll") for (int r = 0; r < 4; r++) {                            \
      p0[r] = EXP2(s0[r] * lam - mnl);                                         \
      p1[r] = EXP2(s1[r] * lam - mnl);                                         \
      p2[r] = EXP2(s2[r] * lam - mnl);                                         \
      p3[r] = EXP2(s3[r] * lam - mnl);                                         \
    }                                                                          \
    f32x4 ps = (p0 + p1) + (p2 + p3);                                          \
    l_r += (ps[0] + ps[1]) + (ps[2] + ps[3]);                                  \
    bf16x4 w0, w1, w2, w3;                                                     \
    _Pragma("unroll") for (int r = 0; r < 4; r++) {                            \
      w0[r] = (__bf16)p0[r]; w1[r] = (__bf16)p1[r];                            \
      w2[r] = (__bf16)p2[r]; w3[r] = (__bf16)p3[r];                            \
    }                                                                          \
    *reinterpret_cast<bf16x4*>(myp + lr * 72 + lk * 4) = w0;                   \
    *reinterpret_cast<bf16x4*>(myp + lr * 72 + 16 + lk * 4) = w1;              \
    *reinterpret_cast<bf16x4*>(myp + lr * 72 + 32 + lk * 4) = w2;              \
    *reinterpret_cast<bf16x4*>(myp + lr * 72 + 48 + lk * 4) = w3;              \
    bf16x8 pa0 = ldb8(myp + lr * 72 + lk * 8);                                 \
    bf16x8 pa1 = ldb8(myp + lr * 72 + 32 + lk * 8);                            \
    __builtin_amdgcn_s_setprio(1);                                             \
    acc[0] = MFMA(ldb8(vb + FADDR(0, 0)), pa0, acc[0]);                        \
    acc[0] = MFMA(ldb8(vb + FADDR(0, 1)), pa1, acc[0]);                        \
    acc[1] = MFMA(ldb8(vb + FADDR(1, 0)), pa0, acc[1]);                        \
    acc[1] = MFMA(ldb8(vb + FADDR(1, 1)), pa1, acc[1]);                        \
    acc[2] = MFMA(ldb8(vb + FADDR(2, 0)), pa0, acc[2]);                        \
    acc[2] = MFMA(ldb8(vb + FADDR(2, 1)), pa1, acc[2]);                        \
    acc[3] = MFMA(ldb8(vb + FADDR(3, 0)), pa0, acc[3]);                        \
    acc[3] = MFMA(ldb8(vb + FADDR(3, 1)), pa1, acc[3]);                        \
    __builtin_amdgcn_s_setprio(0);                                             \
  } while (0)

  STAGE(0, 0);  // prologue
  for (int t = 0; t < NT; t += 2) {
    STEP(t, 0);
    STEP(t + 1, 1);
  }
#undef STEP
#undef STAGE
#undef FADDR

  // cross-lane l reduce (m is already query-uniform by construction)
  l_r += __shfl_xor(l_r, 16);
  l_r += __shfl_xor(l_r, 32);
  float inv_l = 1.f / l_r;
  bf16_t* obase = Opart + (((size_t)z * NH + h) * Nn + q0 + lr) * HD + lk * 4;
#pragma unroll
  for (int dt = 0; dt < 4; dt++) {
    bf16x4 ov;
#pragma unroll
    for (int r = 0; r < 4; r++) ov[r] = (__bf16)(acc[dt][r] * inv_l);
    *reinterpret_cast<bf16x4*>(obase + dt * 16) = ov;
  }
  if (lk == 0) {
    float2 mlv = make_float2(m_r, l_r);
    *reinterpret_cast<float2*>(ml + (((size_t)z * NH + h) * Nn + q0 + lr) * 2) = mlv;
  }
}

// ---------------- merge split-K partials -> At[b][n][c] bf16 ----------------
__global__ __launch_bounds__(256) void attn_merge(const bf16_t* __restrict__ Opart,
    const float* __restrict__ ml, bf16_t* __restrict__ At) {
  int gid = blockIdx.x * 256 + threadIdx.x;
  int d0 = (gid & 7) * 8;
  int q = (gid >> 3) & (Nn - 1);
  int h = (gid >> 15) & (NH - 1);
  int b = gid >> 17;
  const float lam = 0.0625f * 1.44269504088896f;
  size_t zi[NSPLIT];
  float mv[NSPLIT], lv[NSPLIT], wv[NSPLIT];
  float M = -1e30f;
#pragma unroll
  for (int s = 0; s < NSPLIT; s++) {
    zi[s] = ((size_t)(s * Bz + b) * NH + h) * Nn + q;
    mv[s] = ml[zi[s] * 2];
    lv[s] = ml[zi[s] * 2 + 1];
    M = fmaxf(M, mv[s]);
  }
  float L = 0.f;
#pragma unroll
  for (int s = 0; s < NSPLIT; s++) {
    wv[s] = lv[s] * EXP2((mv[s] - M) * lam);
    L += wv[s];
  }
  float invL = 1.f / L;
  float o[8] = {};
#pragma unroll
  for (int s = 0; s < NSPLIT; s++) {
    bf16x8 a = ldb8(Opart + zi[s] * HD + d0);
#pragma unroll
    for (int r = 0; r < 8; r++) o[r] += (float)a[r] * wv[s];
  }
  bf16x8 ov;
#pragma unroll
  for (int r = 0; r < 8; r++) ov[r] = (__bf16)(o[r] * invL);
  *reinterpret_cast<bf16x8*>(At + ((size_t)b * Nn + q) * Cc + h * HD + d0) = ov;
}

// ------ out GEMM + bias + residual (LDS-staged swizzled weight tile) ------
__global__ __launch_bounds__(256) void out_gemm(const bf16_t* __restrict__ At,
    const bf16_t* __restrict__ w, const float* __restrict__ bo,
    const float* __restrict__ x, float* __restrict__ out) {
  int b = blockIdx.z;
  int o0 = blockIdx.y * 64;
  int n0 = blockIdx.x * 64;
  int tid = threadIdx.x;
  int wid = tid >> 6;
  int lane = tid & 63;
  int lr = lane & 15, lk = lane >> 4;

  __shared__ __align__(16) char smem[64 * 256 * 2];   // 32 KB
  bf16_t* wbuf = (bf16_t*)smem;
  float(*t)[68] = (float(*)[68])smem;                 // 17.4 KB, overlaps wbuf

#pragma unroll
  for (int rnd = 0; rnd < 8; rnd++) {
    int u = rnd * 256 + tid;
    int row = u >> 5, cu = u & 31;
    int cus = (cu & 24) | ((cu & 7) ^ (row & 7));
    GLOAD_LDS(w + (size_t)(o0 + row) * Cc + cus * 8, &wbuf[u * 8]);
  }
  const bf16_t* aa = At + ((size_t)b * Nn + n0 + wid * 16 + lr) * Cc + lk * 8;
  f32x4 acc[4] = {};
  __syncthreads();
#pragma unroll
  for (int kk = 0; kk < Cc / 32; kk++) {
    bf16x8 a = ldb8(aa + kk * 32);
#pragma unroll
    for (int os = 0; os < 4; os++) {
      bf16x8 bb = ldb8(&wbuf[(os * 16 + lr) * Cc + (((kk * 4 + lk) ^ (lr & 7)) * 8)]);
      acc[os] = MFMA(a, bb, acc[os]);
    }
  }
  __syncthreads();                     // all wbuf reads done before t overwrite
#pragma unroll
  for (int os = 0; os < 4; os++)
#pragma unroll
    for (int r = 0; r < 4; r++)
      t[wid * 16 + lk * 4 + r][os * 16 + lr] = acc[os][r];
  __syncthreads();
  int orow = tid >> 2;
  int nch = (tid & 3) * 16;
  size_t base = ((size_t)b * Cc + o0 + orow) * Nn + n0 + nch;
  float bv = bo[o0 + orow];
#pragma unroll
  for (int j = 0; j < 16; j++)
    out[base + j] = t[nch + j][orow] + bv + x[base + j];
}

extern "C" void kernel_launch(void* const* d_in, const int* in_sizes, int n_in,
                              void* d_out, int out_size, void* d_ws, size_t ws_size,
                              hipStream_t stream) {
  const float* x = (const float*)d_in[0];
  const float* gn_scale = (const float*)d_in[1];
  const float* gn_bias = (const float*)d_in[2];
  const float* w_qkv = (const float*)d_in[3];
  const float* w_out = (const float*)d_in[4];
  const float* b_out = (const float*)d_in[5];
  float* out = (float*)d_out;
  char* ws = (char*)d_ws;

  // Workspace layout (peak ~29.1 MiB):
  //   [0)        stats4   2 KB
  //   [4096)     wout_b   128 KB
  //   [139264)   Qt       4 MB   (At aliases Qt after attn)
  //   [4333568)  Kt       4 MB
  //   [8527872)  V        4 MB
  //   [12722176) wqkv_b 384 KB + normt 4 MB   -- dead after qkv_gemm
  //   [12722176) Opart (bf16, 8z*4h*4096q*64d = 16 MB)  -- live from attn_kern
  //   [29499392) ml    (fp32, 8z*4h*4096q*2  = 1 MB)
  float* stats4 = (float*)(ws + 0);
  bf16_t* wout_b = (bf16_t*)(ws + 4096);
  bf16_t* Qt = (bf16_t*)(ws + 139264);
  bf16_t* At = (bf16_t*)(ws + 139264);
  bf16_t* Kt = (bf16_t*)(ws + 4333568);
  bf16_t* V = (bf16_t*)(ws + 8527872);
  bf16_t* wqkv_b = (bf16_t*)(ws + 12722176);
  bf16_t* normt = (bf16_t*)(ws + 13115392);
  bf16_t* Opart = (bf16_t*)(ws + 12722176);
  float* ml = (float*)(ws + 29499392);

  conv_w<<<768, 256, 0, stream>>>(w_qkv, w_out, wqkv_b, wout_b);
  gn_reduce<<<dim3(Bz * NG, GNPART), 256, 0, stream>>>(x, stats4);
  gn_apply<<<dim3(Nn / 64, Cc / 64, Bz), 256, 0, stream>>>(x, stats4, gn_scale, gn_bias, normt);
  qkv_gemm<<<dim3(Nn / 128, 12, Bz), 512, 0, stream>>>(normt, wqkv_b, Qt, Kt, V);
  attn_kern<<<dim3(Nn / 128, NH, Bz * NSPLIT), 512, 0, stream>>>(Qt, Kt, V, Opart, ml);
  attn_merge<<<Bz * NH * Nn * HD / 8 / 256, 256, 0, stream>>>(Opart, ml, At);
  out_gemm<<<dim3(Nn / 64, Cc / 64, Bz), 256, 0, stream>>>(At, wout_b, b_out, x, out);
}

// Round 8
// 89.288 us; speedup vs baseline: 3.3947x; 1.0162x over previous
//
#include <hip/hip_runtime.h>
#include <hip/hip_bf16.h>

#define Bz 2
#define Cc 256
#define Nn 4096
#define NH 4
#define HD 64
#define NG 32
#define CPG 8
#define EPSv 1e-5f
#define NSPLIT 4   // key-dim splits for attention
#define GNPART 4   // partial blocks per group in gn_reduce

typedef __bf16 bf16x8 __attribute__((ext_vector_type(8)));
typedef __bf16 bf16x4 __attribute__((ext_vector_type(4)));
typedef float f32x4 __attribute__((ext_vector_type(4)));
using bf16_t = __hip_bfloat16;

#define MFMA(a, b, c) __builtin_amdgcn_mfma_f32_16x16x32_bf16(a, b, c, 0, 0, 0)

#define GLOAD_LDS(g, l)                                                        \
  __builtin_amdgcn_global_load_lds(                                            \
      (const __attribute__((address_space(1))) void*)(g),                      \
      (__attribute__((address_space(3))) void*)(l), 16, 0, 0)

// raw v_exp_f32: softmax args are bounded (defer threshold) and large-negative
// flush-to-zero is the desired behavior; libm's fixup expansion is overhead.
#define EXP2(x)                                                                \
  ({ float _r, _x = (x); asm("v_exp_f32 %0, %1" : "=v"(_r) : "v"(_x)); _r; })

#define MAX3F(a, b, c)                                                         \
  ({ float _m; asm("v_max3_f32 %0, %1, %2, %3"                                 \
                   : "=v"(_m) : "v"(a), "v"(b), "v"(c)); _m; })

__device__ __forceinline__ bf16x8 ldb8(const bf16_t* p) {
  return *reinterpret_cast<const bf16x8*>(p);
}

// ---------------- GroupNorm: partial sums per (b,g,quarter) ----------------
__global__ __launch_bounds__(256) void gn_reduce(const float* __restrict__ x,
                                                 float* __restrict__ stats4) {
  int bg = blockIdx.x;
  int part = blockIdx.y;
  const float4* p4 = reinterpret_cast<const float4*>(
      x + (size_t)bg * (CPG * Nn) + (size_t)part * (CPG * Nn / GNPART));
  float s = 0.f, ss = 0.f;
  for (int i = threadIdx.x; i < CPG * Nn / GNPART / 4; i += 256) {
    float4 v = p4[i];
    s += v.x + v.y + v.z + v.w;
    ss += v.x * v.x + v.y * v.y + v.z * v.z + v.w * v.w;
  }
#pragma unroll
  for (int off = 32; off > 0; off >>= 1) {
    s += __shfl_down(s, off);
    ss += __shfl_down(ss, off);
  }
  __shared__ float ps[4], pss[4];
  int wid = threadIdx.x >> 6;
  if ((threadIdx.x & 63) == 0) { ps[wid] = s; pss[wid] = ss; }
  __syncthreads();
  if (threadIdx.x == 0) {
    stats4[(bg * GNPART + part) * 2] = ps[0] + ps[1] + ps[2] + ps[3];
    stats4[(bg * GNPART + part) * 2 + 1] = pss[0] + pss[1] + pss[2] + pss[3];
  }
}

// ------ GroupNorm apply -> norm_t[b][n][c] bf16, coalesced both sides ------
__global__ __launch_bounds__(256) void gn_apply(const float* __restrict__ x,
    const float* __restrict__ stats4, const float* __restrict__ sc,
    const float* __restrict__ bi, bf16_t* __restrict__ normt) {
  int b = blockIdx.z, c0 = blockIdx.y * 64, n0 = blockIdx.x * 64;
  __shared__ __align__(16) __bf16 t[64][72];
  int cx = threadIdx.x & 15, cy0 = threadIdx.x >> 4;
  const float inv = 1.f / (float)(CPG * Nn);
#pragma unroll
  for (int j = 0; j < 4; j++) {
    int c = c0 + cy0 + j * 16;
    int bg = b * NG + (c >> 3);
    float S = stats4[bg * 8] + stats4[bg * 8 + 2] + stats4[bg * 8 + 4] + stats4[bg * 8 + 6];
    float SS = stats4[bg * 8 + 1] + stats4[bg * 8 + 3] + stats4[bg * 8 + 5] + stats4[bg * 8 + 7];
    float mean = S * inv;
    float rstd = rsqrtf(SS * inv - mean * mean + EPSv);
    float a = rstd * sc[c];
    float bb = bi[c] - mean * a;
    float4 v = *reinterpret_cast<const float4*>(x + ((size_t)b * Cc + c) * Nn + n0 + cx * 4);
    bf16x4 w;
    w[0] = (__bf16)(v.x * a + bb); w[1] = (__bf16)(v.y * a + bb);
    w[2] = (__bf16)(v.z * a + bb); w[3] = (__bf16)(v.w * a + bb);
    *reinterpret_cast<bf16x4*>(&t[cy0 + j * 16][cx * 4]) = w;
  }
  __syncthreads();
  int ny = threadIdx.x >> 2, ch0 = threadIdx.x & 3;
#pragma unroll
  for (int j = 0; j < 2; j++) {
    int ch = ch0 + j * 4;
    bf16x8 o;
#pragma unroll
    for (int jj = 0; jj < 8; jj++) o[jj] = t[ch * 8 + jj][ny];
    *reinterpret_cast<bf16x8*>(normt + ((size_t)b * Nn + n0 + ny) * Cc + c0 + ch * 8) = o;
  }
}

// ---------------- weight fp32 -> bf16 ----------------
__global__ __launch_bounds__(256) void conv_w(const float* __restrict__ wq,
    const float* __restrict__ wo, bf16_t* __restrict__ wqb,
    bf16_t* __restrict__ wob) {
  int i = blockIdx.x * 256 + threadIdx.x;
  if (i < 768 * Cc) wqb[i] = __float2bfloat16(wq[i]);
  if (i < Cc * Cc) wob[i] = __float2bfloat16(wo[i]);
}

// ------- QKV GEMM v2: A-tile in registers, 3 o-tiles (q,k,v of head h) -----
// Per block: load 128n x 256k of normt into regs once; loop q/k/v o-tiles,
// staging each 64x256 weight tile in LDS (16B-unit swizzle cu^=(row&7), rule
// #21 inverse-swizzled global source). Epilogue via bf16 LDS tile for
// b128-coalesced stores.
__global__ __launch_bounds__(512) void qkv_gemm(const bf16_t* __restrict__ normt,
    const bf16_t* __restrict__ w, bf16_t* __restrict__ Qt,
    bf16_t* __restrict__ Kt, bf16_t* __restrict__ V) {
  int b = blockIdx.z;
  int h = blockIdx.y;                 // head index = o-group
  int n0 = blockIdx.x * 128;
  int tid = threadIdx.x;
  int wid = tid >> 6, lane = tid & 63;
  int lr = lane & 15, lk = lane >> 4;

  __shared__ __align__(16) bf16_t wbuf[64 * 256];   // 32 KB
  __shared__ __align__(16) __bf16 tt[128 * 80];     // 20 KB

  const bf16_t* an = normt + ((size_t)b * Nn + n0 + wid * 16 + lr) * Cc + lk * 8;
  bf16x8 a[8];
#pragma unroll
  for (int kk = 0; kk < 8; kk++) a[kk] = ldb8(an + kk * 32);

#pragma unroll
  for (int part = 0; part < 3; part++) {
    int o0 = h * 192 + part * 64;
#pragma unroll
    for (int rnd = 0; rnd < 4; rnd++) {
      int u = rnd * 512 + tid;         // 16B unit: row=u>>5, col-unit=u&31
      int row = u >> 5, cu = u & 31;
      int cus = (cu & 24) | ((cu & 7) ^ (row & 7));
      GLOAD_LDS(w + (size_t)(o0 + row) * Cc + cus * 8, &wbuf[u * 8]);
    }
    __syncthreads();                   // wbuf ready; prev tt reads done
    f32x4 acc[4] = {};
#pragma unroll
    for (int kk = 0; kk < 8; kk++)
#pragma unroll
      for (int os = 0; os < 4; os++) {
        bf16x8 bb = ldb8(&wbuf[(os * 16 + lr) * Cc + (((kk * 4 + lk) ^ (lr & 7)) * 8)]);
        acc[os] = MFMA(a[kk], bb, acc[os]);
      }
#pragma unroll
    for (int os = 0; os < 4; os++)
#pragma unroll
      for (int r = 0; r < 4; r++)
        tt[(wid * 16 + lk * 4 + r) * 80 + os * 16 + lr] = (__bf16)acc[os][r];
    __syncthreads();                   // tt ready; all wbuf reads done
    if (part < 2) {
      bf16_t* dst = (part == 0 ? Qt : Kt) + (size_t)(b * NH + h) * Nn * HD + (size_t)n0 * HD;
      int n = tid >> 2, dch = (tid & 3) * 16;
      bf16x8 o1 = ldb8(reinterpret_cast<const bf16_t*>(&tt[n * 80 + dch]));
      bf16x8 o2 = ldb8(reinterpret_cast<const bf16_t*>(&tt[n * 80 + dch + 8]));
      *reinterpret_cast<bf16x8*>(dst + (size_t)n * HD + dch) = o1;
      *reinterpret_cast<bf16x8*>(dst + (size_t)n * HD + dch + 8) = o2;
    } else {
      bf16_t* dst = V + (size_t)(b * NH + h) * HD * Nn + n0;
      int d = tid >> 3, nch = (tid & 7) * 16;
      bf16x8 o1, o2;
#pragma unroll
      for (int j = 0; j < 8; j++) {
        o1[j] = tt[(nch + j) * 80 + d];
        o2[j] = tt[(nch + 8 + j) * 80 + d];
      }
      *reinterpret_cast<bf16x8*>(dst + (size_t)d * Nn + nch) = o1;
      *reinterpret_cast<bf16x8*>(dst + (size_t)d * Nn + nch + 8) = o2;
    }
  }
}

// ---- Flash attention v3: flat LDS, immediate addressing, KVBLK=64 ----
// Layout (bytes): kbuf[buf] @ buf*8192; vbuf[buf] @ 16384+buf*8192;
// plds @ 32768 + wid*2304 (16 rows x 144B). K/V tiles [64][64] bf16 with
// 16B-unit swizzle c^=(row&7); linear DMA dest + inverse-swizzled global
// source (rule #21). Swapped QK^T: lane (lr,lk) holds S^T for query lr,
// keys {16m+4lk+r}. All ds offsets = 2 per-lane base regs + immediates.
__global__ __launch_bounds__(512, 4) void attn_kern(const bf16_t* __restrict__ Qt,
    const bf16_t* __restrict__ Kt, const bf16_t* __restrict__ V,
    bf16_t* __restrict__ Opart, float* __restrict__ ml) {
  int z = blockIdx.z;          // z = split*Bz + b
  int b = z & 1, sp = z >> 1;
  int h = blockIdx.y;
  int wid = threadIdx.x >> 6, lane = threadIdx.x & 63;
  int lr = lane & 15, lk = lane >> 4;
  int q0 = blockIdx.x * 128 + wid * 16;
  size_t bh = (size_t)(b * NH + h);
  const bf16_t* qp = Qt + (bh * Nn + q0 + lr) * HD + lk * 8;
  bf16x8 aq0 = ldb8(qp), aq1 = ldb8(qp + 32);
  const bf16_t* kglob = Kt + bh * Nn * HD;
  const bf16_t* vglob = V + bh * HD * Nn;
  int kbeg = sp * (Nn / NSPLIT);

  __shared__ __align__(16) char lds[51200];

  // staging source (inverse-swizzled global): 16B-unit u=(wid&3)*64+lane
  int su = (wid & 3) * 64 + lane;
  int srow = su >> 3, scc = su & 7;
  int swz = (scc ^ (srow & 7)) * 8;
  const bf16_t* ksrc = kglob + (size_t)(kbeg + srow) * HD + swz;   // waves 0-3
  const bf16_t* vsrc = vglob + (size_t)srow * Nn + kbeg + swz;     // waves 4-7

  // per-lane LDS byte bases (everything else is compile-time immediates)
  int x0 = lr & 7;
  int aK = lr * 128 + ((lk ^ x0) * 16);   // frag col-unit kk=0
  int aK1 = aK ^ 64;                      // kk=1 ((4+lk)^x0)*16
  int pwo = 32768 + wid * 2304 + lr * 144 + lk * 8;    // P writes (+0,32,64,96)
  int pro = 32768 + wid * 2304 + lr * 144 + lk * 16;   // P reads (+0,64)

  f32x4 acc[4] = {};
  f32x4 lacc = {};
  float m_r = -1e30f;
  const float lam = 0.0625f * 1.44269504088896f;  // (1/sqrt(C)) * log2(e)
  const int NT = (Nn / NSPLIT) / 64;              // 16 (even)

#define LD8(off) (*reinterpret_cast<const bf16x8*>(lds + (off)))

#define STAGE(buf, t)                                                          \
  do {                                                                         \
    if (wid < 4) {                                                             \
      GLOAD_LDS(ksrc + (size_t)(t) * 64 * HD,                                  \
                lds + (buf) * 8192 + (wid & 3) * 1024);                        \
      GLOAD_LDS(ksrc + (size_t)(t) * 64 * HD + 32 * HD,                        \
                lds + (buf) * 8192 + (wid & 3) * 1024 + 4096);                 \
    } else {                                                                   \
      GLOAD_LDS(vsrc + (size_t)(t) * 64,                                       \
                lds + 16384 + (buf) * 8192 + (wid & 3) * 1024);                \
      GLOAD_LDS(vsrc + (size_t)(t) * 64 + (size_t)32 * Nn,                     \
                lds + 16384 + (buf) * 8192 + (wid & 3) * 1024 + 4096);         \
    }                                                                          \
  } while (0)

#define STEP(t, buf)                                                           \
  do {                                                                         \
    __syncthreads();                                                           \
    STAGE(buf ^ 1, (t) + 1);                                                   \
    f32x4 s0 = {}, s1 = {}, s2 = {}, s3 = {};                                  \
    __builtin_amdgcn_s_setprio(1);                                             \
    s0 = MFMA(LD8(aK + (buf) * 8192), aq0, s0);                                \
    s0 = MFMA(LD8(aK1 + (buf) * 8192), aq1, s0);                               \
    s1 = MFMA(LD8(aK + (buf) * 8192 + 2048), aq0, s1);                         \
    s1 = MFMA(LD8(aK1 + (buf) * 8192 + 2048), aq1, s1);                        \
    s2 = MFMA(LD8(aK + (buf) * 8192 + 4096), aq0, s2);                         \
    s2 = MFMA(LD8(aK1 + (buf) * 8192 + 4096), aq1, s2);                        \
    s3 = MFMA(LD8(aK + (buf) * 8192 + 6144), aq0, s3);                         \
    s3 = MFMA(LD8(aK1 + (buf) * 8192 + 6144), aq1, s3);                        \
    __builtin_amdgcn_s_setprio(0);                                             \
    float _t0 = MAX3F(s0[0], s0[1], s0[2]);                                    \
    float _t1 = MAX3F(s0[3], s1[0], s1[1]);                                    \
    float _t2 = MAX3F(s1[2], s1[3], s2[0]);                                    \
    float _t3 = MAX3F(s2[1], s2[2], s2[3]);                                    \
    float _t4 = MAX3F(s3[0], s3[1], s3[2]);                                    \
    float pm = fmaxf(MAX3F(_t0, _t1, _t2), MAX3F(_t3, _t4, s3[3]));            \
    if (!__all(pm <= m_r + 64.f)) {     /* rare: new max beyond defer bound */ \
      float pmw = fmaxf(pm, __shfl_xor(pm, 16));                               \
      pmw = fmaxf(pmw, __shfl_xor(pmw, 32));                                   \
      float mn = fmaxf(m_r, pmw);                                              \
      float sf = EXP2((m_r - mn) * lam);                                       \
      m_r = mn;                                                                \
      lacc = lacc * sf;                                                        \
      acc[0] = acc[0] * sf; acc[1] = acc[1] * sf;                              \
      acc[2] = acc[2] * sf; acc[3] = acc[3] * sf;                              \
    }                                                                          \
    float mnl = m_r * lam;                                                     \
    f32x4 p0, p1, p2, p3;                                                      \
    _Pragma("unroll") for (int r = 0; r < 4; r++) {                            \
      p0[r] = EXP2(s0[r] * lam - mnl);                                         \
      p1[r] = EXP2(s1[r] * lam - mnl);                                         \
      p2[r] = EXP2(s2[r] * lam - mnl);                                         \
      p3[r] = EXP2(s3[r] * lam - mnl);                                         \
    }                                                                          \
    lacc += (p0 + p1) + (p2 + p3);                                             \
    bf16x4 w0, w1, w2, w3;                                                     \
    _Pragma("unroll") for (int r = 0; r < 4; r++) {                            \
      w0[r] = (__bf16)p0[r]; w1[r] = (__bf16)p1[r];                            \
      w2[r] = (__bf16)p2[r]; w3[r] = (__bf16)p3[r];                            \
    }                                                                          \
    *reinterpret_cast<bf16x4*>(lds + pwo) = w0;                                \
    *reinterpret_cast<bf16x4*>(lds + pwo + 32) = w1;                           \
    *reinterpret_cast<bf16x4*>(lds + pwo + 64) = w2;                           \
    *reinterpret_cast<bf16x4*>(lds + pwo + 96) = w3;                           \
    bf16x8 pa0 = LD8(pro);                                                     \
    bf16x8 pa1 = LD8(pro + 64);                                                \
    __builtin_amdgcn_s_setprio(1);                                             \
    acc[0] = MFMA(LD8(aK + 16384 + (buf) * 8192), pa0, acc[0]);                \
    acc[0] = MFMA(LD8(aK1 + 16384 + (buf) * 8192), pa1, acc[0]);               \
    acc[1] = MFMA(LD8(aK + 16384 + (buf) * 8192 + 2048), pa0, acc[1]);         \
    acc[1] = MFMA(LD8(aK1 + 16384 + (buf) * 8192 + 2048), pa1, acc[1]);        \
    acc[2] = MFMA(LD8(aK + 16384 + (buf) * 8192 + 4096), pa0, acc[2]);         \
    acc[2] = MFMA(LD8(aK1 + 16384 + (buf) * 8192 + 4096), pa1, acc[2]);        \
    acc[3] = MFMA(LD8(aK + 16384 + (buf) * 8192 + 6144), pa0, acc[3]);         \
    acc[3] = MFMA(LD8(aK1 + 16384 + (buf) * 8192 + 6144), pa1, acc[3]);        \
    __builtin_amdgcn_s_setprio(0);                                             \
  } while (0)

  STAGE(0, 0);  // prologue
  for (int t = 0; t < NT; t += 2) {
    STEP(t, 0);
    STEP(t + 1, 1);
  }
#undef STEP
#undef STAGE
#undef LD8

  // horizontal + cross-lane l reduce (m is query-uniform by construction)
  float l_r = (lacc[0] + lacc[1]) + (lacc[2] + lacc[3]);
  l_r += __shfl_xor(l_r, 16);
  l_r += __shfl_xor(l_r, 32);
  float inv_l = 1.f / l_r;
  bf16_t* obase = Opart + (((size_t)z * NH + h) * Nn + q0 + lr) * HD + lk * 4;
#pragma unroll
  for (int dt = 0; dt < 4; dt++) {
    bf16x4 ov;
#pragma unroll
    for (int r = 0; r < 4; r++) ov[r] = (__bf16)(acc[dt][r] * inv_l);
    *reinterpret_cast<bf16x4*>(obase + dt * 16) = ov;
  }
  if (lk == 0) {
    float2 mlv = make_float2(m_r, l_r);
    *reinterpret_cast<float2*>(ml + (((size_t)z * NH + h) * Nn + q0 + lr) * 2) = mlv;
  }
}

// ---------------- merge split-K partials -> At[b][n][c] bf16 ----------------
__global__ __launch_bounds__(256) void attn_merge(const bf16_t* __restrict__ Opart,
    const float* __restrict__ ml, bf16_t* __restrict__ At) {
  int gid = blockIdx.x * 256 + threadIdx.x;
  int d0 = (gid & 7) * 8;
  int q = (gid >> 3) & (Nn - 1);
  int h = (gid >> 15) & (NH - 1);
  int b = gid >> 17;
  const float lam = 0.0625f * 1.44269504088896f;
  size_t zi[NSPLIT];
  float mv[NSPLIT], lv[NSPLIT], wv[NSPLIT];
  float M = -1e30f;
#pragma unroll
  for (int s = 0; s < NSPLIT; s++) {
    zi[s] = ((size_t)(s * Bz + b) * NH + h) * Nn + q;
    mv[s] = ml[zi[s] * 2];
    lv[s] = ml[zi[s] * 2 + 1];
    M = fmaxf(M, mv[s]);
  }
  float L = 0.f;
#pragma unroll
  for (int s = 0; s < NSPLIT; s++) {
    wv[s] = lv[s] * EXP2((mv[s] - M) * lam);
    L += wv[s];
  }
  float invL = 1.f / L;
  float o[8] = {};
#pragma unroll
  for (int s = 0; s < NSPLIT; s++) {
    bf16x8 a = ldb8(Opart + zi[s] * HD + d0);
#pragma unroll
    for (int r = 0; r < 8; r++) o[r] += (float)a[r] * wv[s];
  }
  bf16x8 ov;
#pragma unroll
  for (int r = 0; r < 8; r++) ov[r] = (__bf16)(o[r] * invL);
  *reinterpret_cast<bf16x8*>(At + ((size_t)b * Nn + q) * Cc + h * HD + d0) = ov;
}

// ------ out GEMM + bias + residual (LDS-staged swizzled weight tile) ------
__global__ __launch_bounds__(256) void out_gemm(const bf16_t* __restrict__ At,
    const bf16_t* __restrict__ w, const float* __restrict__ bo,
    const float* __restrict__ x, float* __restrict__ out) {
  int b = blockIdx.z;
  int o0 = blockIdx.y * 64;
  int n0 = blockIdx.x * 64;
  int tid = threadIdx.x;
  int wid = tid >> 6;
  int lane = tid & 63;
  int lr = lane & 15, lk = lane >> 4;

  __shared__ __align__(16) char smem[64 * 256 * 2];   // 32 KB
  bf16_t* wbuf = (bf16_t*)smem;
  float(*t)[68] = (float(*)[68])smem;                 // 17.4 KB, overlaps wbuf

#pragma unroll
  for (int rnd = 0; rnd < 8; rnd++) {
    int u = rnd * 256 + tid;
    int row = u >> 5, cu = u & 31;
    int cus = (cu & 24) | ((cu & 7) ^ (row & 7));
    GLOAD_LDS(w + (size_t)(o0 + row) * Cc + cus * 8, &wbuf[u * 8]);
  }
  const bf16_t* aa = At + ((size_t)b * Nn + n0 + wid * 16 + lr) * Cc + lk * 8;
  f32x4 acc[4] = {};
  __syncthreads();
#pragma unroll
  for (int kk = 0; kk < Cc / 32; kk++) {
    bf16x8 a = ldb8(aa + kk * 32);
#pragma unroll
    for (int os = 0; os < 4; os++) {
      bf16x8 bb = ldb8(&wbuf[(os * 16 + lr) * Cc + (((kk * 4 + lk) ^ (lr & 7)) * 8)]);
      acc[os] = MFMA(a, bb, acc[os]);
    }
  }
  __syncthreads();                     // all wbuf reads done before t overwrite
#pragma unroll
  for (int os = 0; os < 4; os++)
#pragma unroll
    for (int r = 0; r < 4; r++)
      t[wid * 16 + lk * 4 + r][os * 16 + lr] = acc[os][r];
  __syncthreads();
  int orow = tid >> 2;
  int nch = (tid & 3) * 16;
  size_t base = ((size_t)b * Cc + o0 + orow) * Nn + n0 + nch;
  float bv = bo[o0 + orow];
#pragma unroll
  for (int j = 0; j < 16; j++)
    out[base + j] = t[nch + j][orow] + bv + x[base + j];
}

extern "C" void kernel_launch(void* const* d_in, const int* in_sizes, int n_in,
                              void* d_out, int out_size, void* d_ws, size_t ws_size,
                              hipStream_t stream) {
  const float* x = (const float*)d_in[0];
  const float* gn_scale = (const float*)d_in[1];
  const float* gn_bias = (const float*)d_in[2];
  const float* w_qkv = (const float*)d_in[3];
  const float* w_out = (const float*)d_in[4];
  const float* b_out = (const float*)d_in[5];
  float* out = (float*)d_out;
  char* ws = (char*)d_ws;

  // Workspace layout (peak ~29.1 MiB):
  //   [0)        stats4   2 KB
  //   [4096)     wout_b   128 KB
  //   [139264)   Qt       4 MB   (At aliases Qt after attn)
  //   [4333568)  Kt       4 MB
  //   [8527872)  V        4 MB
  //   [12722176) wqkv_b 384 KB + normt 4 MB   -- dead after qkv_gemm
  //   [12722176) Opart (bf16, 8z*4h*4096q*64d = 16 MB)  -- live from attn_kern
  //   [29499392) ml    (fp32, 8z*4h*4096q*2  = 1 MB)
  float* stats4 = (float*)(ws + 0);
  bf16_t* wout_b = (bf16_t*)(ws + 4096);
  bf16_t* Qt = (bf16_t*)(ws + 139264);
  bf16_t* At = (bf16_t*)(ws + 139264);
  bf16_t* Kt = (bf16_t*)(ws + 4333568);
  bf16_t* V = (bf16_t*)(ws + 8527872);
  bf16_t* wqkv_b = (bf16_t*)(ws + 12722176);
  bf16_t* normt = (bf16_t*)(ws + 13115392);
  bf16_t* Opart = (bf16_t*)(ws + 12722176);
  float* ml = (float*)(ws + 29499392);

  conv_w<<<768, 256, 0, stream>>>(w_qkv, w_out, wqkv_b, wout_b);
  gn_reduce<<<dim3(Bz * NG, GNPART), 256, 0, stream>>>(x, stats4);
  gn_apply<<<dim3(Nn / 64, Cc / 64, Bz), 256, 0, stream>>>(x, stats4, gn_scale, gn_bias, normt);
  qkv_gemm<<<dim3(Nn / 128, NH, Bz), 512, 0, stream>>>(normt, wqkv_b, Qt, Kt, V);
  attn_kern<<<dim3(Nn / 128, NH, Bz * NSPLIT), 512, 0, stream>>>(Qt, Kt, V, Opart, ml);
  attn_merge<<<Bz * NH * Nn * HD / 8 / 256, 256, 0, stream>>>(Opart, ml, At);
  out_gemm<<<dim3(Nn / 64, Cc / 64, Bz), 256, 0, stream>>>(At, wout_b, b_out, x, out);
}